// Round 12
// baseline (992.605 us; speedup 1.0000x reference)
//
#include <hip/hip_runtime.h>
#include <hip/hip_bf16.h>

typedef float f32x4 __attribute__((ext_vector_type(4)));
typedef short s16x8 __attribute__((ext_vector_type(8)));
typedef unsigned int u32x4 __attribute__((ext_vector_type(4)));

#define DEV static __device__ __forceinline__

DEV unsigned short f2bf(float x){
    unsigned u = __builtin_bit_cast(unsigned, x);
    u += 0x7FFFu + ((u >> 16) & 1u);
    return (unsigned short)(u >> 16);
}
DEV float bf2f(unsigned short h){
    unsigned u = ((unsigned)h) << 16;
    return __builtin_bit_cast(float, u);
}
DEV float sigm_(float x){ return __builtin_amdgcn_rcpf(1.0f + __expf(-x)); }
DEV float silu_(float x){ return x * sigm_(x); }

DEV int xcd_swz(){
    int bid = blockIdx.x, nwg = gridDim.x;
    return (bid & 7) * (nwg >> 3) + (bid >> 3);
}

// ---------------- weight transpose + convert
__global__ __launch_bounds__(256) void k_transconv(const float* __restrict__ src,
                                                   unsigned short* __restrict__ dst,
                                                   int K, int total){
    int gid = blockIdx.x * 256 + threadIdx.x;
    if (gid >= total) return;
    int kn  = K * 64;
    int b   = gid / kn;
    int rem = gid - b * kn;
    int k   = rem >> 6, n = rem & 63;
    dst[b * kn + n * K + k] = f2bf(src[gid]);
}

__global__ __launch_bounds__(256) void k_embed(const float* __restrict__ emb,
                                               const int* __restrict__ z,
                                               unsigned short* __restrict__ out){
    int gid = blockIdx.x * 256 + threadIdx.x;
    int n = gid >> 6, f = gid & 63;
    out[gid] = f2bf(emb[z[n] * 64 + f]);
}

__global__ __launch_bounds__(256) void k_smallmm(const float* __restrict__ bases,
                                                 const float* __restrict__ W,
                                                 unsigned short* __restrict__ out){
    int gid = blockIdx.x * 256 + threadIdx.x;
    int r = gid >> 6, f = gid & 63;
    const float* b = bases + r * 9;
    float acc = 0.f;
    #pragma unroll
    for (int k = 0; k < 9; ++k) acc += b[k] * W[k * 64 + f];
    out[gid] = f2bf(acc);
}

__global__ __launch_bounds__(256) void k_smallmm_perm(const float* __restrict__ bases,
                                                      const float* __restrict__ W,
                                                      const int* __restrict__ perm,
                                                      unsigned short* __restrict__ out){
    int gid = blockIdx.x * 256 + threadIdx.x;
    int r = gid >> 6, f = gid & 63;
    const float* b = bases + (size_t)perm[r] * 9;
    float acc = 0.f;
    #pragma unroll
    for (int k = 0; k < 9; ++k) acc += b[k] * W[k * 64 + f];
    out[gid] = f2bf(acc);
}

// ---------------- CSR build helpers
__global__ void k_count(const int* __restrict__ dst, int stride, int n, int* __restrict__ cnt){
    int i = blockIdx.x * 256 + threadIdx.x;
    if (i < n) atomicAdd(&cnt[dst[(size_t)i * stride]], 1);
}

__global__ __launch_bounds__(256) void k_bsum(const int* __restrict__ cnt,
                                              int* __restrict__ bsum){
    int i = blockIdx.x * 256 + threadIdx.x;
    int v = cnt[i];
    #pragma unroll
    for (int off = 32; off > 0; off >>= 1) v += __shfl_down(v, off);
    __shared__ int ws[4];
    if ((threadIdx.x & 63) == 0) ws[threadIdx.x >> 6] = v;
    __syncthreads();
    if (threadIdx.x == 0) bsum[blockIdx.x] = ws[0] + ws[1] + ws[2] + ws[3];
}

__global__ __launch_bounds__(256) void k_bscan(const int* __restrict__ bsum,
                                               int* __restrict__ bbase, int nb,
                                               int* __restrict__ total_out){
    __shared__ int sh[256];
    int t = threadIdx.x;
    int v = (t < nb) ? bsum[t] : 0;
    sh[t] = v;
    __syncthreads();
    for (int d = 1; d < 256; d <<= 1){
        int u = (t >= d) ? sh[t - d] : 0;
        __syncthreads();
        sh[t] += u;
        __syncthreads();
    }
    if (t < nb) bbase[t] = sh[t] - v;
    if (t == nb - 1) *total_out = sh[t];
}

__global__ __launch_bounds__(256) void k_offs(const int* __restrict__ cnt,
                                              const int* __restrict__ bbase,
                                              int* __restrict__ offs){
    __shared__ int sh[256];
    int t = threadIdx.x;
    int i = blockIdx.x * 256 + t;
    int v = cnt[i];
    sh[t] = v;
    __syncthreads();
    for (int d = 1; d < 256; d <<= 1){
        int u = (t >= d) ? sh[t - d] : 0;
        __syncthreads();
        sh[t] += u;
        __syncthreads();
    }
    offs[i] = bbase[blockIdx.x] + sh[t] - v;
}

__global__ void k_fill(const int* __restrict__ dst, int stride, int n,
                       const int* __restrict__ offs, int* __restrict__ cur,
                       int* __restrict__ idx){
    int i = blockIdx.x * 256 + threadIdx.x;
    if (i < n){
        int d = dst[(size_t)i * stride];
        int p = offs[d] + atomicAdd(&cur[d], 1);
        idx[p] = i;
    }
}

// ---------------- gather-reduce (contiguous)
__global__ __launch_bounds__(256) void k_reduce(const unsigned short* __restrict__ upd,
                                                const int* __restrict__ offs,
                                                unsigned short* __restrict__ act, int nRows){
    int gid = blockIdx.x * 256 + threadIdx.x;
    int row = gid >> 3;
    if (row >= nRows) return;
    int c8 = (gid & 7) * 8;
    int o = offs[row], e = offs[row + 1];
    float acc[8] = {};
    for (int j = o; j < e; ++j){
        s16x8 v = *(const s16x8*)&upd[(size_t)j * 64 + c8];
        #pragma unroll
        for (int q = 0; q < 8; ++q) acc[q] += bf2f((unsigned short)v[q]);
    }
    s16x8 a = *(s16x8*)&act[(size_t)row * 64 + c8];
    #pragma unroll
    for (int q = 0; q < 8; ++q) a[q] = (short)f2bf(bf2f((unsigned short)a[q]) + acc[q]);
    *(s16x8*)&act[(size_t)row * 64 + c8] = a;
}

#define MFMA16(a,b,c) __builtin_amdgcn_mfma_f32_16x16x32_bf16(a,b,c,0,0,0)

// ================= atom-conv body, BM=32 =================
// smem layout: [0,7104) overlay {ldsA [32][200]=6400 | HC/HG/V [32][74] at 0/2368/4736},
//              [8448,10624) ldsBw [32][68]
DEV void atom_body(unsigned short* smem, int* ldsSrc, int bid,
    const unsigned short* atomBf, const unsigned short* bondBf,
    const unsigned short* bwagBf,
    const int* agraph, const int* d2u, const int* idxA,
    const unsigned short* w1cT, const unsigned short* w1gT,
    const unsigned short* w2cT, const unsigned short* w2gT,
    const unsigned short* woT,
    const float* cb1, const float* cb2, const float* gb1, const float* gb2,
    unsigned short* upd)
{
    unsigned short* ldsA  = smem;
    unsigned short* ldsHC = smem;
    unsigned short* ldsHG = smem + 2368;
    unsigned short* ldsV  = smem + 4736;
    unsigned short* ldsBw = smem + 8448;
    const int tid = threadIdx.x;
    const int r0  = bid * 32;

    if (tid < 128){   // q: 0=atom[ag0] 1=bond[d2u] 2=atom[ag1] 3=bw[d2u]
        int q = tid >> 5, row = tid & 31;
        int e = idxA[r0 + row];
        int s;
        if (q == 0)      s = agraph[2 * e];
        else if (q == 1) s = d2u[e];
        else if (q == 2) s = agraph[2 * e + 1];
        else             s = d2u[e];
        ldsSrc[tid] = s;
    }
    __syncthreads();
    {
        const int lane8 = tid & 7;
        #pragma unroll
        for (int p = 0; p < 4; ++p){
            int cc = p * 32 + (tid >> 3);
            int q = cc >> 5, row = cc & 31;
            int s = ldsSrc[cc];
            const unsigned short* buf = (q == 1) ? bondBf : atomBf;
            if (q == 3) buf = bwagBf;
            u32x4 v = *(const u32x4*)(buf + (size_t)s * 64 + lane8 * 8);
            if (q < 3) *(u32x4*)&ldsA[row * 200 + q * 64 + lane8 * 8] = v;
            else       *(u32x4*)&ldsBw[row * 68 + lane8 * 8] = v;
        }
    }
    __syncthreads();

    const int lane = tid & 63;
    const int r16  = lane & 15;
    const int grp  = lane >> 4;
    const int col  = (tid >> 6) * 16 + r16;

    f32x4 aC[2] = {}, aG[2] = {};
    #pragma unroll
    for (int kt = 0; kt < 6; ++kt){
        s16x8 bc = *(const s16x8*)&w1cT[col * 192 + kt * 32 + grp * 8];
        s16x8 bg = *(const s16x8*)&w1gT[col * 192 + kt * 32 + grp * 8];
        #pragma unroll
        for (int mt = 0; mt < 2; ++mt){
            s16x8 a = *(const s16x8*)&ldsA[(mt * 16 + r16) * 200 + kt * 32 + grp * 8];
            aC[mt] = MFMA16(a, bc, aC[mt]);
            aG[mt] = MFMA16(a, bg, aG[mt]);
        }
    }
    __syncthreads();   // ldsA dead; overlay writable

    const float bC1 = cb1[col], bG1 = gb1[col];
    #pragma unroll
    for (int mt = 0; mt < 2; ++mt){
        #pragma unroll
        for (int j = 0; j < 4; ++j){
            int row = mt * 16 + grp * 4 + j;
            ldsHC[row * 74 + col] = f2bf(silu_(aC[mt][j] + bC1));
            ldsHG[row * 74 + col] = f2bf(silu_(aG[mt][j] + bG1));
        }
    }
    __syncthreads();

    f32x4 oC[2] = {}, oG[2] = {};
    #pragma unroll
    for (int kt = 0; kt < 2; ++kt){
        s16x8 bc = *(const s16x8*)&w2cT[col * 64 + kt * 32 + grp * 8];
        s16x8 bg = *(const s16x8*)&w2gT[col * 64 + kt * 32 + grp * 8];
        #pragma unroll
        for (int mt = 0; mt < 2; ++mt){
            s16x8 hc = *(const s16x8*)&ldsHC[(mt * 16 + r16) * 74 + kt * 32 + grp * 8];
            s16x8 hg = *(const s16x8*)&ldsHG[(mt * 16 + r16) * 74 + kt * 32 + grp * 8];
            oC[mt] = MFMA16(hc, bc, oC[mt]);
            oG[mt] = MFMA16(hg, bg, oG[mt]);
        }
    }
    const float bC2 = cb2[col], bG2 = gb2[col];
    #pragma unroll
    for (int mt = 0; mt < 2; ++mt){
        #pragma unroll
        for (int j = 0; j < 4; ++j){
            int row = mt * 16 + grp * 4 + j;
            float v = silu_(oC[mt][j] + bC2) * sigm_(oG[mt][j] + bG2);
            v *= bf2f(ldsBw[row * 68 + col]);
            ldsV[row * 74 + col] = f2bf(v);
        }
    }
    __syncthreads();

    f32x4 oD[2] = {};
    #pragma unroll
    for (int kt = 0; kt < 2; ++kt){
        s16x8 bo = *(const s16x8*)&woT[col * 64 + kt * 32 + grp * 8];
        #pragma unroll
        for (int mt = 0; mt < 2; ++mt){
            s16x8 a = *(const s16x8*)&ldsV[(mt * 16 + r16) * 74 + kt * 32 + grp * 8];
            oD[mt] = MFMA16(a, bo, oD[mt]);
        }
    }
    #pragma unroll
    for (int mt = 0; mt < 2; ++mt){
        #pragma unroll
        for (int j = 0; j < 4; ++j){
            int row = mt * 16 + grp * 4 + j;
            upd[(size_t)(r0 + row) * 64 + col] = f2bf(oD[mt][j]);
        }
    }
}

// ================= angle body, BM=32 (angle in sorted space) =================
DEV void angle_body(unsigned short* ldsA, int* ldsSrc, int bid,
    const unsigned short* atomBf, const unsigned short* bondBf,
    unsigned short* angleS,
    const int* bga, const int* bgb, const int* idxB,
    const unsigned short* wcT, const unsigned short* wgT,
    const float* cb, const float* gb)
{
    const int tid = threadIdx.x;
    const int r0  = bid * 32;

    if (tid < 128){   // q: 0=bond[bgi] 1=bond[bgj] 2=angle(contig) 3=atom[bga]
        int q = tid >> 5, row = tid & 31;
        int s;
        if (q == 2) s = r0 + row;
        else {
            int a = idxB[r0 + row];
            if (q == 0)      s = bgb[2 * a];
            else if (q == 1) s = bgb[2 * a + 1];
            else             s = bga[a];
        }
        ldsSrc[tid] = s;
    }
    __syncthreads();
    {
        const int lane8 = tid & 7;
        #pragma unroll
        for (int p = 0; p < 4; ++p){
            int cc = p * 32 + (tid >> 3);
            int q = cc >> 5, row = cc & 31;
            int s = ldsSrc[cc];
            const unsigned short* buf = (q < 2) ? bondBf : (q == 2 ? angleS : atomBf);
            u32x4 v = *(const u32x4*)(buf + (size_t)s * 64 + lane8 * 8);
            *(u32x4*)&ldsA[row * 264 + q * 64 + lane8 * 8] = v;
        }
    }
    __syncthreads();

    const int lane = tid & 63;
    const int r16  = lane & 15;
    const int grp  = lane >> 4;
    const int col  = (tid >> 6) * 16 + r16;

    f32x4 aC[2] = {}, aG[2] = {};
    #pragma unroll
    for (int kt = 0; kt < 8; ++kt){
        s16x8 bc = *(const s16x8*)&wcT[col * 256 + kt * 32 + grp * 8];
        s16x8 bg = *(const s16x8*)&wgT[col * 256 + kt * 32 + grp * 8];
        #pragma unroll
        for (int mt = 0; mt < 2; ++mt){
            s16x8 a = *(const s16x8*)&ldsA[(mt * 16 + r16) * 264 + kt * 32 + grp * 8];
            aC[mt] = MFMA16(a, bc, aC[mt]);
            aG[mt] = MFMA16(a, bg, aG[mt]);
        }
    }
    const float bC = cb[col], bG = gb[col];
    #pragma unroll
    for (int mt = 0; mt < 2; ++mt){
        #pragma unroll
        for (int j = 0; j < 4; ++j){
            int row = mt * 16 + grp * 4 + j;
            float oldv = bf2f(ldsA[row * 264 + 128 + col]);
            float v = silu_(aC[mt][j] + bC) * sigm_(aG[mt][j] + bG);
            angleS[(size_t)(r0 + row) * 64 + col] = f2bf(oldv + v);
        }
    }
}

// ---------------- standalone atom conv (first iteration), BM=32
__global__ __launch_bounds__(256, 6) void k_atom_conv(
    const unsigned short* __restrict__ atomBf, const unsigned short* __restrict__ bondBf,
    const unsigned short* __restrict__ bwagBf,
    const int* __restrict__ agraph, const int* __restrict__ d2u,
    const int* __restrict__ idxA,
    const unsigned short* __restrict__ w1cT, const unsigned short* __restrict__ w1gT,
    const unsigned short* __restrict__ w2cT, const unsigned short* __restrict__ w2gT,
    const unsigned short* __restrict__ woT,
    const float* __restrict__ cb1, const float* __restrict__ cb2,
    const float* __restrict__ gb1, const float* __restrict__ gb2,
    unsigned short* __restrict__ upd)
{
    __shared__ __align__(16) unsigned short smem[10624];
    __shared__ int ldsSrc[128];
    atom_body(smem, ldsSrc, xcd_swz(),
              atomBf, bondBf, bwagBf, agraph, d2u, idxA,
              w1cT, w1gT, w2cT, w2gT, woT, cb1, cb2, gb1, gb2, upd);
}

// ---------------- fused: angle update (iter i) + atom conv (iter i+1), BM=32
__global__ __launch_bounds__(256, 6) void k_angle_atom(
    const unsigned short* __restrict__ atomBf, const unsigned short* __restrict__ bondBf,
    unsigned short* __restrict__ angleS, const unsigned short* __restrict__ bwagBf,
    const int* __restrict__ agraph, const int* __restrict__ d2u, const int* __restrict__ idxA,
    const int* __restrict__ bga, const int* __restrict__ bgb, const int* __restrict__ idxB,
    const unsigned short* __restrict__ an_wcT, const unsigned short* __restrict__ an_wgT,
    const float* __restrict__ an_cb, const float* __restrict__ an_gb,
    const unsigned short* __restrict__ ac_w1cT, const unsigned short* __restrict__ ac_w1gT,
    const unsigned short* __restrict__ ac_w2cT, const unsigned short* __restrict__ ac_w2gT,
    const unsigned short* __restrict__ ac_woT,
    const float* __restrict__ ac_cb1, const float* __restrict__ ac_cb2,
    const float* __restrict__ ac_gb1, const float* __restrict__ ac_gb2,
    unsigned short* __restrict__ upd, int nbAngle)
{
    __shared__ __align__(16) unsigned short smem[10624];
    __shared__ int ldsSrc[128];
    int bid = blockIdx.x;
    if (bid < nbAngle){
        angle_body(smem, ldsSrc, bid, atomBf, bondBf, angleS, bga, bgb, idxB,
                   an_wcT, an_wgT, an_cb, an_gb);
    } else {
        atom_body(smem, ldsSrc, bid - nbAngle,
                  atomBf, bondBf, bwagBf, agraph, d2u, idxA,
                  ac_w1cT, ac_w1gT, ac_w2cT, ac_w2gT, ac_woT,
                  ac_cb1, ac_cb2, ac_gb1, ac_gb2, upd);
    }
}

// ---------------- bond conv, BM=32 (angle read from sorted space)
__global__ __launch_bounds__(256, 6) void k_bond_conv(
    const unsigned short* __restrict__ atomBf, const unsigned short* __restrict__ bondBf,
    const unsigned short* __restrict__ angleS, const unsigned short* __restrict__ bwbgBf,
    const int* __restrict__ bga, const int* __restrict__ bgb,
    const int* __restrict__ idxB,
    const unsigned short* __restrict__ w1cT, const unsigned short* __restrict__ w1gT,
    const unsigned short* __restrict__ w2cT, const unsigned short* __restrict__ w2gT,
    const unsigned short* __restrict__ woT,
    const float* __restrict__ cb1, const float* __restrict__ cb2,
    const float* __restrict__ gb1, const float* __restrict__ gb2,
    unsigned short* __restrict__ upd)
{
    __shared__ __align__(16) unsigned short lds[8448];   // ldsA [32][264]; overlay HC/HG/V [32][74]
    __shared__ int ldsSrc[128];
    unsigned short* ldsA  = lds;
    unsigned short* ldsHC = lds;
    unsigned short* ldsHG = lds + 2368;
    unsigned short* ldsV  = lds + 4736;
    const int tid = threadIdx.x;
    const int r0  = xcd_swz() * 32;

    if (tid < 128){
        int q = tid >> 5, row = tid & 31;
        int s;
        if (q == 2) s = r0 + row;
        else {
            int a = idxB[r0 + row];
            if (q == 0)      s = bgb[2 * a];
            else if (q == 1) s = bgb[2 * a + 1];
            else             s = bga[a];
        }
        ldsSrc[tid] = s;
    }
    __syncthreads();
    {
        const int lane8 = tid & 7;
        #pragma unroll
        for (int p = 0; p < 4; ++p){
            int cc = p * 32 + (tid >> 3);
            int q = cc >> 5, row = cc & 31;
            int s = ldsSrc[cc];
            const unsigned short* buf = (q < 2) ? bondBf : (q == 2 ? angleS : atomBf);
            u32x4 v = *(const u32x4*)(buf + (size_t)s * 64 + lane8 * 8);
            *(u32x4*)&ldsA[row * 264 + q * 64 + lane8 * 8] = v;
        }
    }
    __syncthreads();

    const int lane = tid & 63;
    const int r16  = lane & 15;
    const int grp  = lane >> 4;
    const int col  = (tid >> 6) * 16 + r16;

    unsigned short bwv[8];
    #pragma unroll
    for (int mt = 0; mt < 2; ++mt)
        #pragma unroll
        for (int j = 0; j < 4; ++j)
            bwv[mt * 4 + j] = bwbgBf[(size_t)ldsSrc[mt * 16 + grp * 4 + j] * 64 + col];

    f32x4 aC[2] = {}, aG[2] = {};
    #pragma unroll
    for (int kt = 0; kt < 8; ++kt){
        s16x8 bc = *(const s16x8*)&w1cT[col * 256 + kt * 32 + grp * 8];
        s16x8 bg = *(const s16x8*)&w1gT[col * 256 + kt * 32 + grp * 8];
        #pragma unroll
        for (int mt = 0; mt < 2; ++mt){
            s16x8 a = *(const s16x8*)&ldsA[(mt * 16 + r16) * 264 + kt * 32 + grp * 8];
            aC[mt] = MFMA16(a, bc, aC[mt]);
            aG[mt] = MFMA16(a, bg, aG[mt]);
        }
    }
    __syncthreads();

    const float bC1 = cb1[col], bG1 = gb1[col];
    #pragma unroll
    for (int mt = 0; mt < 2; ++mt){
        #pragma unroll
        for (int j = 0; j < 4; ++j){
            int row = mt * 16 + grp * 4 + j;
            ldsHC[row * 74 + col] = f2bf(silu_(aC[mt][j] + bC1));
            ldsHG[row * 74 + col] = f2bf(silu_(aG[mt][j] + bG1));
        }
    }
    __syncthreads();

    f32x4 oC[2] = {}, oG[2] = {};
    #pragma unroll
    for (int kt = 0; kt < 2; ++kt){
        s16x8 bc = *(const s16x8*)&w2cT[col * 64 + kt * 32 + grp * 8];
        s16x8 bg = *(const s16x8*)&w2gT[col * 64 + kt * 32 + grp * 8];
        #pragma unroll
        for (int mt = 0; mt < 2; ++mt){
            s16x8 hc = *(const s16x8*)&ldsHC[(mt * 16 + r16) * 74 + kt * 32 + grp * 8];
            s16x8 hg = *(const s16x8*)&ldsHG[(mt * 16 + r16) * 74 + kt * 32 + grp * 8];
            oC[mt] = MFMA16(hc, bc, oC[mt]);
            oG[mt] = MFMA16(hg, bg, oG[mt]);
        }
    }
    const float bC2 = cb2[col], bG2 = gb2[col];
    #pragma unroll
    for (int mt = 0; mt < 2; ++mt){
        #pragma unroll
        for (int j = 0; j < 4; ++j){
            int row = mt * 16 + grp * 4 + j;
            float v = silu_(oC[mt][j] + bC2) * sigm_(oG[mt][j] + bG2);
            v *= bf2f(bwv[mt * 4 + j]);
            ldsV[row * 74 + col] = f2bf(v);
        }
    }
    __syncthreads();

    f32x4 oD[2] = {};
    #pragma unroll
    for (int kt = 0; kt < 2; ++kt){
        s16x8 bo = *(const s16x8*)&woT[col * 64 + kt * 32 + grp * 8];
        #pragma unroll
        for (int mt = 0; mt < 2; ++mt){
            s16x8 a = *(const s16x8*)&ldsV[(mt * 16 + r16) * 74 + kt * 32 + grp * 8];
            oD[mt] = MFMA16(a, bo, oD[mt]);
        }
    }
    #pragma unroll
    for (int mt = 0; mt < 2; ++mt){
        #pragma unroll
        for (int j = 0; j < 4; ++j){
            int row = mt * 16 + grp * 4 + j;
            upd[(size_t)(r0 + row) * 64 + col] = f2bf(oD[mt][j]);
        }
    }
}

// ---------------- readout MLP + segmented sum
__global__ __launch_bounds__(256) void k_readout(
    const unsigned short* __restrict__ atomBf, const int* __restrict__ owners,
    const float* __restrict__ w1, const float* __restrict__ b1,
    const float* __restrict__ w2, const float* __restrict__ b2,
    const float* __restrict__ w3, const float* __restrict__ b3,
    float* __restrict__ esum, float* __restrict__ cnt)
{
    int gid  = blockIdx.x * 256 + threadIdx.x;
    int n    = gid >> 6;
    int lane = threadIdx.x & 63;
    float a = bf2f(atomBf[n * 64 + lane]);
    float acc = b1[lane];
    #pragma unroll
    for (int k = 0; k < 64; ++k) acc += __shfl(a, k) * w1[k * 64 + lane];
    float h = silu_(acc);
    acc = b2[lane];
    #pragma unroll
    for (int k = 0; k < 64; ++k) acc += __shfl(h, k) * w2[k * 64 + lane];
    h = silu_(acc);
    float p = h * w3[lane];
    #pragma unroll
    for (int off = 32; off > 0; off >>= 1) p += __shfl_xor(p, off);
    if (lane == 0){
        atomicAdd(&esum[owners[n]], p + b3[0]);
        atomicAdd(&cnt[owners[n]], 1.0f);
    }
}

__global__ void k_final(const float* __restrict__ esum, const float* __restrict__ cnt,
                        float* __restrict__ out){
    int i = threadIdx.x;
    if (i < 128) out[i] = esum[i] / fmaxf(cnt[i], 1.0f);
}

extern "C" void kernel_launch(void* const* d_in, const int* in_sizes, int n_in,
                              void* d_out, int out_size, void* d_ws, size_t ws_size,
                              hipStream_t stream)
{
    (void)in_sizes; (void)n_in; (void)out_size; (void)ws_size;
    const int N_ATOMS = 8192, N_UND = 65536, N_DIR = 131072, N_ANG = 262144;

    const int*   atomic_numbers = (const int*)  d_in[0];
    const float* bb_ag  = (const float*)d_in[1];
    const float* bb_bg  = (const float*)d_in[2];
    const float* ang_b  = (const float*)d_in[3];
    const int*   agraph = (const int*)  d_in[4];
    const int*   d2u    = (const int*)  d_in[5];
    const int*   bga    = (const int*)  d_in[6];
    const int*   bgb    = (const int*)  d_in[7];
    const int*   owners = (const int*)  d_in[8];
    const float* emb    = (const float*)d_in[9];
    const float* Wb     = (const float*)d_in[10];
    const float* Wa     = (const float*)d_in[11];
    const float* Wbwag  = (const float*)d_in[12];
    const float* Wbwbg  = (const float*)d_in[13];
    const float* ac_cw1 = (const float*)d_in[14];
    const float* ac_cb1 = (const float*)d_in[15];
    const float* ac_cw2 = (const float*)d_in[16];
    const float* ac_cb2 = (const float*)d_in[17];
    const float* ac_gw1 = (const float*)d_in[18];
    const float* ac_gb1 = (const float*)d_in[19];
    const float* ac_gw2 = (const float*)d_in[20];
    const float* ac_gb2 = (const float*)d_in[21];
    const float* ac_out = (const float*)d_in[22];
    const float* bc_cw1 = (const float*)d_in[23];
    const float* bc_cb1 = (const float*)d_in[24];
    const float* bc_cw2 = (const float*)d_in[25];
    const float* bc_cb2 = (const float*)d_in[26];
    const float* bc_gw1 = (const float*)d_in[27];
    const float* bc_gb1 = (const float*)d_in[28];
    const float* bc_gw2 = (const float*)d_in[29];
    const float* bc_gb2 = (const float*)d_in[30];
    const float* bc_out = (const float*)d_in[31];
    const float* an_cw  = (const float*)d_in[32];
    const float* an_cb  = (const float*)d_in[33];
    const float* an_gw  = (const float*)d_in[34];
    const float* an_gb  = (const float*)d_in[35];
    const float* ro_w1  = (const float*)d_in[36];
    const float* ro_b1  = (const float*)d_in[37];
    const float* ro_w2  = (const float*)d_in[38];
    const float* ro_b2  = (const float*)d_in[39];
    const float* ro_w3  = (const float*)d_in[40];
    const float* ro_b3  = (const float*)d_in[41];

    char* ws = (char*)d_ws;
    size_t off = 0;
    auto alloc = [&](size_t bytes) -> void* {
        void* p = ws + off;
        off = (off + bytes + 255) & ~(size_t)255;
        return p;
    };
    unsigned short* atomBf  = (unsigned short*)alloc((size_t)N_ATOMS * 64 * 2);
    unsigned short* bondBf  = (unsigned short*)alloc((size_t)N_UND   * 64 * 2);
    unsigned short* angleS  = (unsigned short*)alloc((size_t)N_ANG   * 64 * 2);
    unsigned short* bwagBf  = (unsigned short*)alloc((size_t)N_UND   * 64 * 2);
    unsigned short* bwbgBf  = (unsigned short*)alloc((size_t)N_UND   * 64 * 2);
    unsigned short* updBuf  = (unsigned short*)alloc((size_t)N_ANG   * 64 * 2);
    float* esum   = (float*)alloc(128 * 4);
    float* cnt    = (float*)alloc(128 * 4);
    int* offsA = (int*)alloc((N_ATOMS + 1) * 4);
    int* curA  = (int*)alloc(N_ATOMS * 4);
    int* idxA  = (int*)alloc((size_t)N_DIR * 4);
    int* offsB = (int*)alloc((N_UND + 1) * 4);
    int* curB  = (int*)alloc(N_UND * 4);
    int* idxB  = (int*)alloc((size_t)N_ANG * 4);
    int* bsum  = (int*)alloc(256 * 4);
    int* bbase = (int*)alloc(256 * 4);
    unsigned short* acw1cT = (unsigned short*)alloc((size_t)4 * 64 * 192 * 2);
    unsigned short* acw1gT = (unsigned short*)alloc((size_t)4 * 64 * 192 * 2);
    unsigned short* acw2cT = (unsigned short*)alloc((size_t)4 * 64 * 64 * 2);
    unsigned short* acw2gT = (unsigned short*)alloc((size_t)4 * 64 * 64 * 2);
    unsigned short* acoT   = (unsigned short*)alloc((size_t)4 * 64 * 64 * 2);
    unsigned short* bcw1cT = (unsigned short*)alloc((size_t)3 * 64 * 256 * 2);
    unsigned short* bcw1gT = (unsigned short*)alloc((size_t)3 * 64 * 256 * 2);
    unsigned short* bcw2cT = (unsigned short*)alloc((size_t)3 * 64 * 64 * 2);
    unsigned short* bcw2gT = (unsigned short*)alloc((size_t)3 * 64 * 64 * 2);
    unsigned short* bcoT   = (unsigned short*)alloc((size_t)3 * 64 * 64 * 2);
    unsigned short* anwcT  = (unsigned short*)alloc((size_t)3 * 64 * 256 * 2);
    unsigned short* anwgT  = (unsigned short*)alloc((size_t)3 * 64 * 256 * 2);

    // CSR build first (idxB needed by permuted angle init)
    hipMemsetAsync(curA, 0, N_ATOMS * 4, stream);
    k_count<<<(N_DIR + 255) / 256, 256, 0, stream>>>(agraph, 2, N_DIR, curA);
    k_bsum <<<N_ATOMS / 256, 256, 0, stream>>>(curA, bsum);
    k_bscan<<<1, 256, 0, stream>>>(bsum, bbase, N_ATOMS / 256, offsA + N_ATOMS);
    k_offs <<<N_ATOMS / 256, 256, 0, stream>>>(curA, bbase, offsA);
    hipMemsetAsync(curA, 0, N_ATOMS * 4, stream);
    k_fill<<<(N_DIR + 255) / 256, 256, 0, stream>>>(agraph, 2, N_DIR, offsA, curA, idxA);

    hipMemsetAsync(curB, 0, N_UND * 4, stream);
    k_count<<<(N_ANG + 255) / 256, 256, 0, stream>>>(bgb, 2, N_ANG, curB);
    k_bsum <<<N_UND / 256, 256, 0, stream>>>(curB, bsum);
    k_bscan<<<1, 256, 0, stream>>>(bsum, bbase, N_UND / 256, offsB + N_UND);
    k_offs <<<N_UND / 256, 256, 0, stream>>>(curB, bbase, offsB);
    hipMemsetAsync(curB, 0, N_UND * 4, stream);
    k_fill<<<(N_ANG + 255) / 256, 256, 0, stream>>>(bgb, 2, N_ANG, offsB, curB, idxB);

    auto tc = [&](const float* src, unsigned short* dst, int B, int K){
        int total = B * K * 64;
        k_transconv<<<(total + 255) / 256, 256, 0, stream>>>(src, dst, K, total);
    };
    tc(ac_cw1, acw1cT, 4, 192);  tc(ac_gw1, acw1gT, 4, 192);
    tc(ac_cw2, acw2cT, 4, 64);   tc(ac_gw2, acw2gT, 4, 64);
    tc(ac_out, acoT,   4, 64);
    tc(bc_cw1, bcw1cT, 3, 256);  tc(bc_gw1, bcw1gT, 3, 256);
    tc(bc_cw2, bcw2cT, 3, 64);   tc(bc_gw2, bcw2gT, 3, 64);
    tc(bc_out, bcoT,   3, 64);
    tc(an_cw,  anwcT,  3, 256);  tc(an_gw,  anwgT,  3, 256);

    k_embed<<<N_ATOMS * 64 / 256, 256, 0, stream>>>(emb, atomic_numbers, atomBf);
    k_smallmm<<<N_UND * 64 / 256, 256, 0, stream>>>(bb_ag, Wb,    bondBf);
    k_smallmm_perm<<<N_ANG * 64 / 256, 256, 0, stream>>>(ang_b, Wa, idxB, angleS);
    k_smallmm<<<N_UND * 64 / 256, 256, 0, stream>>>(bb_ag, Wbwag, bwagBf);
    k_smallmm<<<N_UND * 64 / 256, 256, 0, stream>>>(bb_bg, Wbwbg, bwbgBf);

    // iteration 0 atom conv
    k_atom_conv<<<N_DIR / 32, 256, 0, stream>>>(
        atomBf, bondBf, bwagBf, agraph, d2u, idxA,
        acw1cT, acw1gT, acw2cT, acw2gT, acoT,
        ac_cb1, ac_cb2, ac_gb1, ac_gb2, updBuf);
    k_reduce<<<N_ATOMS * 8 / 256, 256, 0, stream>>>(updBuf, offsA, atomBf, N_ATOMS);

    const int NB_AN = N_ANG / 32;      // 8192
    const int NB_AC = N_DIR / 32;      // 4096
    for (int i = 0; i < 3; ++i){
        k_bond_conv<<<NB_AN, 256, 0, stream>>>(
            atomBf, bondBf, angleS, bwbgBf, bga, bgb, idxB,
            bcw1cT + (size_t)i * 64 * 256, bcw1gT + (size_t)i * 64 * 256,
            bcw2cT + (size_t)i * 64 * 64,  bcw2gT + (size_t)i * 64 * 64,
            bcoT   + (size_t)i * 64 * 64,
            bc_cb1 + i * 64, bc_cb2 + i * 64, bc_gb1 + i * 64, bc_gb2 + i * 64, updBuf);
        k_reduce<<<N_UND * 8 / 256, 256, 0, stream>>>(updBuf, offsB, bondBf, N_UND);
        k_angle_atom<<<NB_AN + NB_AC, 256, 0, stream>>>(
            atomBf, bondBf, angleS, bwagBf,
            agraph, d2u, idxA, bga, bgb, idxB,
            anwcT + (size_t)i * 64 * 256, anwgT + (size_t)i * 64 * 256,
            an_cb + i * 64, an_gb + i * 64,
            acw1cT + (size_t)(i + 1) * 64 * 192, acw1gT + (size_t)(i + 1) * 64 * 192,
            acw2cT + (size_t)(i + 1) * 64 * 64,  acw2gT + (size_t)(i + 1) * 64 * 64,
            acoT   + (size_t)(i + 1) * 64 * 64,
            ac_cb1 + (i + 1) * 64, ac_cb2 + (i + 1) * 64,
            ac_gb1 + (i + 1) * 64, ac_gb2 + (i + 1) * 64,
            updBuf, NB_AN);
        k_reduce<<<N_ATOMS * 8 / 256, 256, 0, stream>>>(updBuf, offsA, atomBf, N_ATOMS);
    }

    hipMemsetAsync(esum, 0, 128 * 4, stream);
    hipMemsetAsync(cnt,  0, 128 * 4, stream);
    k_readout<<<N_ATOMS * 64 / 256, 256, 0, stream>>>(
        atomBf, owners, ro_w1, ro_b1, ro_w2, ro_b2, ro_w3, ro_b3, esum, cnt);
    k_final<<<1, 128, 0, stream>>>(esum, cnt, (float*)d_out);
}

// Round 13
// 842.447 us; speedup vs baseline: 1.1782x; 1.1782x over previous
//
#include <hip/hip_runtime.h>
#include <hip/hip_bf16.h>

typedef float f32x4 __attribute__((ext_vector_type(4)));
typedef short s16x8 __attribute__((ext_vector_type(8)));
typedef unsigned int u32x4 __attribute__((ext_vector_type(4)));

#define DEV static __device__ __forceinline__

DEV unsigned short f2bf(float x){
    unsigned u = __builtin_bit_cast(unsigned, x);
    u += 0x7FFFu + ((u >> 16) & 1u);
    return (unsigned short)(u >> 16);
}
DEV float bf2f(unsigned short h){
    unsigned u = ((unsigned)h) << 16;
    return __builtin_bit_cast(float, u);
}
DEV float sigm_(float x){ return __builtin_amdgcn_rcpf(1.0f + __expf(-x)); }
DEV float silu_(float x){ return x * sigm_(x); }

DEV int xcd_swz(){
    int bid = blockIdx.x, nwg = gridDim.x;
    return (bid & 7) * (nwg >> 3) + (bid >> 3);
}

// ---------------- weight transpose + convert (single and paired)
__global__ __launch_bounds__(256) void k_transconv(const float* __restrict__ src,
                                                   unsigned short* __restrict__ dst,
                                                   int K, int total){
    int gid = blockIdx.x * 256 + threadIdx.x;
    if (gid >= total) return;
    int kn  = K * 64;
    int b   = gid / kn;
    int rem = gid - b * kn;
    int k   = rem >> 6, n = rem & 63;
    dst[b * kn + n * K + k] = f2bf(src[gid]);
}

__global__ __launch_bounds__(256) void k_transconv2(const float* __restrict__ s1,
                                                    const float* __restrict__ s2,
                                                    unsigned short* __restrict__ d1,
                                                    unsigned short* __restrict__ d2,
                                                    int K, int total){
    int gid = blockIdx.x * 256 + threadIdx.x;
    if (gid >= total) return;
    int kn  = K * 64;
    int b   = gid / kn;
    int rem = gid - b * kn;
    int k   = rem >> 6, n = rem & 63;
    int o   = b * kn + n * K + k;
    d1[o] = f2bf(s1[gid]);
    d2[o] = f2bf(s2[gid]);
}

__global__ __launch_bounds__(256) void k_embed(const float* __restrict__ emb,
                                               const int* __restrict__ z,
                                               unsigned short* __restrict__ out){
    int gid = blockIdx.x * 256 + threadIdx.x;
    int n = gid >> 6, f = gid & 63;
    out[gid] = f2bf(emb[z[n] * 64 + f]);
}

// bond features + both bond weights in one pass
__global__ __launch_bounds__(256) void k_smallmm3(const float* __restrict__ bag,
                                                  const float* __restrict__ bbg,
                                                  const float* __restrict__ Wb,
                                                  const float* __restrict__ Wwag,
                                                  const float* __restrict__ Wwbg,
                                                  unsigned short* __restrict__ bond,
                                                  unsigned short* __restrict__ bwag,
                                                  unsigned short* __restrict__ bwbg){
    int gid = blockIdx.x * 256 + threadIdx.x;
    int r = gid >> 6, f = gid & 63;
    const float* a = bag + (size_t)r * 9;
    const float* b = bbg + (size_t)r * 9;
    float s1 = 0.f, s2 = 0.f, s3 = 0.f;
    #pragma unroll
    for (int k = 0; k < 9; ++k){
        float av = a[k];
        s1 += av * Wb[k * 64 + f];
        s2 += av * Wwag[k * 64 + f];
        s3 += b[k] * Wwbg[k * 64 + f];
    }
    bond[gid] = f2bf(s1);
    bwag[gid] = f2bf(s2);
    bwbg[gid] = f2bf(s3);
}

__global__ __launch_bounds__(256) void k_smallmm_perm(const float* __restrict__ bases,
                                                      const float* __restrict__ W,
                                                      const int* __restrict__ perm,
                                                      unsigned short* __restrict__ out){
    int gid = blockIdx.x * 256 + threadIdx.x;
    int r = gid >> 6, f = gid & 63;
    const float* b = bases + (size_t)perm[r] * 9;
    float acc = 0.f;
    #pragma unroll
    for (int k = 0; k < 9; ++k) acc += b[k] * W[k * 64 + f];
    out[gid] = f2bf(acc);
}

// ---------------- CSR build helpers
__global__ void k_count(const int* __restrict__ dst, int stride, int n, int* __restrict__ cnt){
    int i = blockIdx.x * 256 + threadIdx.x;
    if (i < n) atomicAdd(&cnt[dst[(size_t)i * stride]], 1);
}

__global__ __launch_bounds__(256) void k_bsum(const int* __restrict__ cnt,
                                              int* __restrict__ bsum){
    int i = blockIdx.x * 256 + threadIdx.x;
    int v = cnt[i];
    #pragma unroll
    for (int off = 32; off > 0; off >>= 1) v += __shfl_down(v, off);
    __shared__ int ws[4];
    if ((threadIdx.x & 63) == 0) ws[threadIdx.x >> 6] = v;
    __syncthreads();
    if (threadIdx.x == 0) bsum[blockIdx.x] = ws[0] + ws[1] + ws[2] + ws[3];
}

__global__ __launch_bounds__(256) void k_bscan(const int* __restrict__ bsum,
                                               int* __restrict__ bbase, int nb,
                                               int* __restrict__ total_out){
    __shared__ int sh[256];
    int t = threadIdx.x;
    int v = (t < nb) ? bsum[t] : 0;
    sh[t] = v;
    __syncthreads();
    for (int d = 1; d < 256; d <<= 1){
        int u = (t >= d) ? sh[t - d] : 0;
        __syncthreads();
        sh[t] += u;
        __syncthreads();
    }
    if (t < nb) bbase[t] = sh[t] - v;
    if (t == nb - 1) *total_out = sh[t];
}

__global__ __launch_bounds__(256) void k_offs(const int* __restrict__ cnt,
                                              const int* __restrict__ bbase,
                                              int* __restrict__ offs){
    __shared__ int sh[256];
    int t = threadIdx.x;
    int i = blockIdx.x * 256 + t;
    int v = cnt[i];
    sh[t] = v;
    __syncthreads();
    for (int d = 1; d < 256; d <<= 1){
        int u = (t >= d) ? sh[t - d] : 0;
        __syncthreads();
        sh[t] += u;
        __syncthreads();
    }
    offs[i] = bbase[blockIdx.x] + sh[t] - v;
}

__global__ void k_fill(const int* __restrict__ dst, int stride, int n,
                       const int* __restrict__ offs, int* __restrict__ cur,
                       int* __restrict__ idx){
    int i = blockIdx.x * 256 + threadIdx.x;
    if (i < n){
        int d = dst[(size_t)i * stride];
        int p = offs[d] + atomicAdd(&cur[d], 1);
        idx[p] = i;
    }
}

// ---------------- source tables (iteration-invariant)
__global__ void k_mktabA(const int* __restrict__ agraph, const int* __restrict__ d2u,
                         const int* __restrict__ idxA, int4* __restrict__ srcA, int n){
    int i = blockIdx.x * 256 + threadIdx.x;
    if (i < n){
        int e = idxA[i];
        int u = d2u[e];
        srcA[i] = make_int4(agraph[2 * e], u, agraph[2 * e + 1], u);
    }
}
__global__ void k_mktabB(const int* __restrict__ bga, const int* __restrict__ bgb,
                         const int* __restrict__ idxB, int4* __restrict__ srcB, int n){
    int i = blockIdx.x * 256 + threadIdx.x;
    if (i < n){
        int a = idxB[i];
        srcB[i] = make_int4(bgb[2 * a], bgb[2 * a + 1], i, bga[a]);
    }
}

// ---------------- gather-reduce (contiguous)
__global__ __launch_bounds__(256) void k_reduce(const unsigned short* __restrict__ upd,
                                                const int* __restrict__ offs,
                                                unsigned short* __restrict__ act, int nRows){
    int gid = blockIdx.x * 256 + threadIdx.x;
    int row = gid >> 3;
    if (row >= nRows) return;
    int c8 = (gid & 7) * 8;
    int o = offs[row], e = offs[row + 1];
    float acc[8] = {};
    for (int j = o; j < e; ++j){
        s16x8 v = *(const s16x8*)&upd[(size_t)j * 64 + c8];
        #pragma unroll
        for (int q = 0; q < 8; ++q) acc[q] += bf2f((unsigned short)v[q]);
    }
    s16x8 a = *(s16x8*)&act[(size_t)row * 64 + c8];
    #pragma unroll
    for (int q = 0; q < 8; ++q) a[q] = (short)f2bf(bf2f((unsigned short)a[q]) + acc[q]);
    *(s16x8*)&act[(size_t)row * 64 + c8] = a;
}

#define MFMA16(a,b,c) __builtin_amdgcn_mfma_f32_16x16x32_bf16(a,b,c,0,0,0)

// ================= atom-conv body (table-driven staging, 4 barriers) =================
DEV void atom_body(unsigned short* smem, int bid,
    const unsigned short* atomBf, const unsigned short* bondBf,
    const unsigned short* bwagBf, const int* srcA,
    const unsigned short* w1cT, const unsigned short* w1gT,
    const unsigned short* w2cT, const unsigned short* w2gT,
    const unsigned short* woT,
    const float* cb1, const float* cb2, const float* gb1, const float* gb2,
    unsigned short* upd)
{
    unsigned short* ldsA  = smem;
    unsigned short* ldsHC = smem;
    unsigned short* ldsHG = smem + 4736;
    unsigned short* ldsV  = smem + 9472;
    unsigned short* ldsBw = smem + 14208;   // [64][68]
    const int tid = threadIdx.x;
    const int r0  = bid * 64;

    {
        const int lane8 = tid & 7;
        #pragma unroll
        for (int p = 0; p < 8; ++p){
            int cc = p * 32 + (tid >> 3);
            int q = cc >> 6, row = cc & 63;
            int s = srcA[(size_t)(r0 + row) * 4 + q];
            const unsigned short* buf = (q == 1 || q == 3) ? bondBf : atomBf;
            if (q == 3) buf = bwagBf;
            u32x4 v = *(const u32x4*)(buf + (size_t)s * 64 + lane8 * 8);
            if (q < 3) *(u32x4*)&ldsA[row * 200 + q * 64 + lane8 * 8] = v;
            else       *(u32x4*)&ldsBw[row * 68 + lane8 * 8] = v;
        }
    }
    __syncthreads();

    const int lane = tid & 63;
    const int r16  = lane & 15;
    const int grp  = lane >> 4;
    const int col  = (tid >> 6) * 16 + r16;

    f32x4 aC[4] = {}, aG[4] = {};
    #pragma unroll
    for (int kt = 0; kt < 6; ++kt){
        s16x8 bc = *(const s16x8*)&w1cT[col * 192 + kt * 32 + grp * 8];
        s16x8 bg = *(const s16x8*)&w1gT[col * 192 + kt * 32 + grp * 8];
        #pragma unroll
        for (int mt = 0; mt < 4; ++mt){
            s16x8 a = *(const s16x8*)&ldsA[(mt * 16 + r16) * 200 + kt * 32 + grp * 8];
            aC[mt] = MFMA16(a, bc, aC[mt]);
            aG[mt] = MFMA16(a, bg, aG[mt]);
        }
    }
    __syncthreads();   // ldsA dead; overlay writable

    const float bC1 = cb1[col], bG1 = gb1[col];
    #pragma unroll
    for (int mt = 0; mt < 4; ++mt){
        #pragma unroll
        for (int j = 0; j < 4; ++j){
            int row = mt * 16 + grp * 4 + j;
            ldsHC[row * 74 + col] = f2bf(silu_(aC[mt][j] + bC1));
            ldsHG[row * 74 + col] = f2bf(silu_(aG[mt][j] + bG1));
        }
    }
    __syncthreads();

    f32x4 oC[4] = {}, oG[4] = {};
    #pragma unroll
    for (int kt = 0; kt < 2; ++kt){
        s16x8 bc = *(const s16x8*)&w2cT[col * 64 + kt * 32 + grp * 8];
        s16x8 bg = *(const s16x8*)&w2gT[col * 64 + kt * 32 + grp * 8];
        #pragma unroll
        for (int mt = 0; mt < 4; ++mt){
            s16x8 hc = *(const s16x8*)&ldsHC[(mt * 16 + r16) * 74 + kt * 32 + grp * 8];
            s16x8 hg = *(const s16x8*)&ldsHG[(mt * 16 + r16) * 74 + kt * 32 + grp * 8];
            oC[mt] = MFMA16(hc, bc, oC[mt]);
            oG[mt] = MFMA16(hg, bg, oG[mt]);
        }
    }
    const float bC2 = cb2[col], bG2 = gb2[col];
    #pragma unroll
    for (int mt = 0; mt < 4; ++mt){
        #pragma unroll
        for (int j = 0; j < 4; ++j){
            int row = mt * 16 + grp * 4 + j;
            float v = silu_(oC[mt][j] + bC2) * sigm_(oG[mt][j] + bG2);
            v *= bf2f(ldsBw[row * 68 + col]);
            ldsV[row * 74 + col] = f2bf(v);
        }
    }
    __syncthreads();

    f32x4 oD[4] = {};
    #pragma unroll
    for (int kt = 0; kt < 2; ++kt){
        s16x8 bo = *(const s16x8*)&woT[col * 64 + kt * 32 + grp * 8];
        #pragma unroll
        for (int mt = 0; mt < 4; ++mt){
            s16x8 a = *(const s16x8*)&ldsV[(mt * 16 + r16) * 74 + kt * 32 + grp * 8];
            oD[mt] = MFMA16(a, bo, oD[mt]);
        }
    }
    #pragma unroll
    for (int mt = 0; mt < 4; ++mt){
        #pragma unroll
        for (int j = 0; j < 4; ++j){
            int row = mt * 16 + grp * 4 + j;
            upd[(size_t)(r0 + row) * 64 + col] = f2bf(oD[mt][j]);
        }
    }
}

// ================= angle body (table-driven, angle in sorted space) =================
DEV void angle_body(unsigned short* ldsA, int bid,
    const unsigned short* atomBf, const unsigned short* bondBf,
    unsigned short* angleS, const int* srcB,
    const unsigned short* wcT, const unsigned short* wgT,
    const float* cb, const float* gb)
{
    const int tid = threadIdx.x;
    const int r0  = bid * 64;

    {
        const int lane8 = tid & 7;
        #pragma unroll
        for (int p = 0; p < 8; ++p){
            int cc = p * 32 + (tid >> 3);
            int q = cc >> 6, row = cc & 63;
            int s = srcB[(size_t)(r0 + row) * 4 + q];
            const unsigned short* buf = (q < 2) ? bondBf : (q == 2 ? angleS : atomBf);
            u32x4 v = *(const u32x4*)(buf + (size_t)s * 64 + lane8 * 8);
            *(u32x4*)&ldsA[row * 264 + q * 64 + lane8 * 8] = v;
        }
    }
    __syncthreads();

    const int lane = tid & 63;
    const int r16  = lane & 15;
    const int grp  = lane >> 4;
    const int col  = (tid >> 6) * 16 + r16;

    f32x4 aC[4] = {}, aG[4] = {};
    #pragma unroll
    for (int kt = 0; kt < 8; ++kt){
        s16x8 bc = *(const s16x8*)&wcT[col * 256 + kt * 32 + grp * 8];
        s16x8 bg = *(const s16x8*)&wgT[col * 256 + kt * 32 + grp * 8];
        #pragma unroll
        for (int mt = 0; mt < 4; ++mt){
            s16x8 a = *(const s16x8*)&ldsA[(mt * 16 + r16) * 264 + kt * 32 + grp * 8];
            aC[mt] = MFMA16(a, bc, aC[mt]);
            aG[mt] = MFMA16(a, bg, aG[mt]);
        }
    }
    const float bC = cb[col], bG = gb[col];
    #pragma unroll
    for (int mt = 0; mt < 4; ++mt){
        #pragma unroll
        for (int j = 0; j < 4; ++j){
            int row = mt * 16 + grp * 4 + j;
            float oldv = bf2f(ldsA[row * 264 + 128 + col]);
            float v = silu_(aC[mt][j] + bC) * sigm_(aG[mt][j] + bG);
            angleS[(size_t)(r0 + row) * 64 + col] = f2bf(oldv + v);
        }
    }
}

// ---------------- standalone atom conv (first iteration)
__global__ __launch_bounds__(256, 4) void k_atom_conv(
    const unsigned short* __restrict__ atomBf, const unsigned short* __restrict__ bondBf,
    const unsigned short* __restrict__ bwagBf, const int* __restrict__ srcA,
    const unsigned short* __restrict__ w1cT, const unsigned short* __restrict__ w1gT,
    const unsigned short* __restrict__ w2cT, const unsigned short* __restrict__ w2gT,
    const unsigned short* __restrict__ woT,
    const float* __restrict__ cb1, const float* __restrict__ cb2,
    const float* __restrict__ gb1, const float* __restrict__ gb2,
    unsigned short* __restrict__ upd)
{
    __shared__ __align__(16) unsigned short smem[18560];
    atom_body(smem, xcd_swz(), atomBf, bondBf, bwagBf, srcA,
              w1cT, w1gT, w2cT, w2gT, woT, cb1, cb2, gb1, gb2, upd);
}

// ---------------- fused: angle update (iter i) + atom conv (iter i+1)
__global__ __launch_bounds__(256, 4) void k_angle_atom(
    const unsigned short* __restrict__ atomBf, const unsigned short* __restrict__ bondBf,
    unsigned short* __restrict__ angleS, const unsigned short* __restrict__ bwagBf,
    const int* __restrict__ srcA, const int* __restrict__ srcB,
    const unsigned short* __restrict__ an_wcT, const unsigned short* __restrict__ an_wgT,
    const float* __restrict__ an_cb, const float* __restrict__ an_gb,
    const unsigned short* __restrict__ ac_w1cT, const unsigned short* __restrict__ ac_w1gT,
    const unsigned short* __restrict__ ac_w2cT, const unsigned short* __restrict__ ac_w2gT,
    const unsigned short* __restrict__ ac_woT,
    const float* __restrict__ ac_cb1, const float* __restrict__ ac_cb2,
    const float* __restrict__ ac_gb1, const float* __restrict__ ac_gb2,
    unsigned short* __restrict__ upd, int nbAngle)
{
    __shared__ __align__(16) unsigned short smem[18560];
    int bid = blockIdx.x;
    if (bid < nbAngle){
        angle_body(smem, bid, atomBf, bondBf, angleS, srcB,
                   an_wcT, an_wgT, an_cb, an_gb);
    } else {
        atom_body(smem, bid - nbAngle, atomBf, bondBf, bwagBf, srcA,
                  ac_w1cT, ac_w1gT, ac_w2cT, ac_w2gT, ac_woT,
                  ac_cb1, ac_cb2, ac_gb1, ac_gb2, upd);
    }
}

// ---------------- bond conv (table-driven)
__global__ __launch_bounds__(256, 4) void k_bond_conv(
    const unsigned short* __restrict__ atomBf, const unsigned short* __restrict__ bondBf,
    const unsigned short* __restrict__ angleS, const unsigned short* __restrict__ bwbgBf,
    const int* __restrict__ srcB,
    const unsigned short* __restrict__ w1cT, const unsigned short* __restrict__ w1gT,
    const unsigned short* __restrict__ w2cT, const unsigned short* __restrict__ w2gT,
    const unsigned short* __restrict__ woT,
    const float* __restrict__ cb1, const float* __restrict__ cb2,
    const float* __restrict__ gb1, const float* __restrict__ gb2,
    unsigned short* __restrict__ upd)
{
    __shared__ __align__(16) unsigned short lds[16896];
    unsigned short* ldsA  = lds;
    unsigned short* ldsHC = lds;
    unsigned short* ldsHG = lds + 4736;
    unsigned short* ldsV  = lds + 9472;
    const int tid = threadIdx.x;
    const int r0  = xcd_swz() * 64;

    {
        const int lane8 = tid & 7;
        #pragma unroll
        for (int p = 0; p < 8; ++p){
            int cc = p * 32 + (tid >> 3);
            int q = cc >> 6, row = cc & 63;
            int s = srcB[(size_t)(r0 + row) * 4 + q];
            const unsigned short* buf = (q < 2) ? bondBf : (q == 2 ? angleS : atomBf);
            u32x4 v = *(const u32x4*)(buf + (size_t)s * 64 + lane8 * 8);
            *(u32x4*)&ldsA[row * 264 + q * 64 + lane8 * 8] = v;
        }
    }
    __syncthreads();

    const int lane = tid & 63;
    const int r16  = lane & 15;
    const int grp  = lane >> 4;
    const int col  = (tid >> 6) * 16 + r16;

    // bw gather via table (bgi), L1-hot after staging
    unsigned short bwv[16];
    #pragma unroll
    for (int mt = 0; mt < 4; ++mt)
        #pragma unroll
        for (int j = 0; j < 4; ++j){
            int row = mt * 16 + grp * 4 + j;
            bwv[mt * 4 + j] = bwbgBf[(size_t)srcB[(size_t)(r0 + row) * 4] * 64 + col];
        }

    f32x4 aC[4] = {}, aG[4] = {};
    #pragma unroll
    for (int kt = 0; kt < 8; ++kt){
        s16x8 bc = *(const s16x8*)&w1cT[col * 256 + kt * 32 + grp * 8];
        s16x8 bg = *(const s16x8*)&w1gT[col * 256 + kt * 32 + grp * 8];
        #pragma unroll
        for (int mt = 0; mt < 4; ++mt){
            s16x8 a = *(const s16x8*)&ldsA[(mt * 16 + r16) * 264 + kt * 32 + grp * 8];
            aC[mt] = MFMA16(a, bc, aC[mt]);
            aG[mt] = MFMA16(a, bg, aG[mt]);
        }
    }
    __syncthreads();

    const float bC1 = cb1[col], bG1 = gb1[col];
    #pragma unroll
    for (int mt = 0; mt < 4; ++mt){
        #pragma unroll
        for (int j = 0; j < 4; ++j){
            int row = mt * 16 + grp * 4 + j;
            ldsHC[row * 74 + col] = f2bf(silu_(aC[mt][j] + bC1));
            ldsHG[row * 74 + col] = f2bf(silu_(aG[mt][j] + bG1));
        }
    }
    __syncthreads();

    f32x4 oC[4] = {}, oG[4] = {};
    #pragma unroll
    for (int kt = 0; kt < 2; ++kt){
        s16x8 bc = *(const s16x8*)&w2cT[col * 64 + kt * 32 + grp * 8];
        s16x8 bg = *(const s16x8*)&w2gT[col * 64 + kt * 32 + grp * 8];
        #pragma unroll
        for (int mt = 0; mt < 4; ++mt){
            s16x8 hc = *(const s16x8*)&ldsHC[(mt * 16 + r16) * 74 + kt * 32 + grp * 8];
            s16x8 hg = *(const s16x8*)&ldsHG[(mt * 16 + r16) * 74 + kt * 32 + grp * 8];
            oC[mt] = MFMA16(hc, bc, oC[mt]);
            oG[mt] = MFMA16(hg, bg, oG[mt]);
        }
    }
    const float bC2 = cb2[col], bG2 = gb2[col];
    #pragma unroll
    for (int mt = 0; mt < 4; ++mt){
        #pragma unroll
        for (int j = 0; j < 4; ++j){
            int row = mt * 16 + grp * 4 + j;
            float v = silu_(oC[mt][j] + bC2) * sigm_(oG[mt][j] + bG2);
            v *= bf2f(bwv[mt * 4 + j]);
            ldsV[row * 74 + col] = f2bf(v);
        }
    }
    __syncthreads();

    f32x4 oD[4] = {};
    #pragma unroll
    for (int kt = 0; kt < 2; ++kt){
        s16x8 bo = *(const s16x8*)&woT[col * 64 + kt * 32 + grp * 8];
        #pragma unroll
        for (int mt = 0; mt < 4; ++mt){
            s16x8 a = *(const s16x8*)&ldsV[(mt * 16 + r16) * 74 + kt * 32 + grp * 8];
            oD[mt] = MFMA16(a, bo, oD[mt]);
        }
    }
    #pragma unroll
    for (int mt = 0; mt < 4; ++mt){
        #pragma unroll
        for (int j = 0; j < 4; ++j){
            int row = mt * 16 + grp * 4 + j;
            upd[(size_t)(r0 + row) * 64 + col] = f2bf(oD[mt][j]);
        }
    }
}

// ---------------- readout MLP + segmented sum
__global__ __launch_bounds__(256) void k_readout(
    const unsigned short* __restrict__ atomBf, const int* __restrict__ owners,
    const float* __restrict__ w1, const float* __restrict__ b1,
    const float* __restrict__ w2, const float* __restrict__ b2,
    const float* __restrict__ w3, const float* __restrict__ b3,
    float* __restrict__ esum, float* __restrict__ cnt)
{
    int gid  = blockIdx.x * 256 + threadIdx.x;
    int n    = gid >> 6;
    int lane = threadIdx.x & 63;
    float a = bf2f(atomBf[n * 64 + lane]);
    float acc = b1[lane];
    #pragma unroll
    for (int k = 0; k < 64; ++k) acc += __shfl(a, k) * w1[k * 64 + lane];
    float h = silu_(acc);
    acc = b2[lane];
    #pragma unroll
    for (int k = 0; k < 64; ++k) acc += __shfl(h, k) * w2[k * 64 + lane];
    h = silu_(acc);
    float p = h * w3[lane];
    #pragma unroll
    for (int off = 32; off > 0; off >>= 1) p += __shfl_xor(p, off);
    if (lane == 0){
        atomicAdd(&esum[owners[n]], p + b3[0]);
        atomicAdd(&cnt[owners[n]], 1.0f);
    }
}

__global__ void k_final(const float* __restrict__ esum, const float* __restrict__ cnt,
                        float* __restrict__ out){
    int i = threadIdx.x;
    if (i < 128) out[i] = esum[i] / fmaxf(cnt[i], 1.0f);
}

extern "C" void kernel_launch(void* const* d_in, const int* in_sizes, int n_in,
                              void* d_out, int out_size, void* d_ws, size_t ws_size,
                              hipStream_t stream)
{
    (void)in_sizes; (void)n_in; (void)out_size; (void)ws_size;
    const int N_ATOMS = 8192, N_UND = 65536, N_DIR = 131072, N_ANG = 262144;

    const int*   atomic_numbers = (const int*)  d_in[0];
    const float* bb_ag  = (const float*)d_in[1];
    const float* bb_bg  = (const float*)d_in[2];
    const float* ang_b  = (const float*)d_in[3];
    const int*   agraph = (const int*)  d_in[4];
    const int*   d2u    = (const int*)  d_in[5];
    const int*   bga    = (const int*)  d_in[6];
    const int*   bgb    = (const int*)  d_in[7];
    const int*   owners = (const int*)  d_in[8];
    const float* emb    = (const float*)d_in[9];
    const float* Wb     = (const float*)d_in[10];
    const float* Wa     = (const float*)d_in[11];
    const float* Wbwag  = (const float*)d_in[12];
    const float* Wbwbg  = (const float*)d_in[13];
    const float* ac_cw1 = (const float*)d_in[14];
    const float* ac_cb1 = (const float*)d_in[15];
    const float* ac_cw2 = (const float*)d_in[16];
    const float* ac_cb2 = (const float*)d_in[17];
    const float* ac_gw1 = (const float*)d_in[18];
    const float* ac_gb1 = (const float*)d_in[19];
    const float* ac_gw2 = (const float*)d_in[20];
    const float* ac_gb2 = (const float*)d_in[21];
    const float* ac_out = (const float*)d_in[22];
    const float* bc_cw1 = (const float*)d_in[23];
    const float* bc_cb1 = (const float*)d_in[24];
    const float* bc_cw2 = (const float*)d_in[25];
    const float* bc_cb2 = (const float*)d_in[26];
    const float* bc_gw1 = (const float*)d_in[27];
    const float* bc_gb1 = (const float*)d_in[28];
    const float* bc_gw2 = (const float*)d_in[29];
    const float* bc_gb2 = (const float*)d_in[30];
    const float* bc_out = (const float*)d_in[31];
    const float* an_cw  = (const float*)d_in[32];
    const float* an_cb  = (const float*)d_in[33];
    const float* an_gw  = (const float*)d_in[34];
    const float* an_gb  = (const float*)d_in[35];
    const float* ro_w1  = (const float*)d_in[36];
    const float* ro_b1  = (const float*)d_in[37];
    const float* ro_w2  = (const float*)d_in[38];
    const float* ro_b2  = (const float*)d_in[39];
    const float* ro_w3  = (const float*)d_in[40];
    const float* ro_b3  = (const float*)d_in[41];

    char* ws = (char*)d_ws;
    size_t off = 0;
    auto alloc = [&](size_t bytes) -> void* {
        void* p = ws + off;
        off = (off + bytes + 255) & ~(size_t)255;
        return p;
    };
    unsigned short* atomBf  = (unsigned short*)alloc((size_t)N_ATOMS * 64 * 2);
    unsigned short* bondBf  = (unsigned short*)alloc((size_t)N_UND   * 64 * 2);
    unsigned short* angleS  = (unsigned short*)alloc((size_t)N_ANG   * 64 * 2);
    unsigned short* bwagBf  = (unsigned short*)alloc((size_t)N_UND   * 64 * 2);
    unsigned short* bwbgBf  = (unsigned short*)alloc((size_t)N_UND   * 64 * 2);
    unsigned short* updBuf  = (unsigned short*)alloc((size_t)N_ANG   * 64 * 2);
    float* esum   = (float*)alloc(128 * 4);
    float* cnt    = (float*)alloc(128 * 4);
    int* offsA = (int*)alloc((N_ATOMS + 1) * 4);
    int* curA  = (int*)alloc(N_ATOMS * 4);
    int* idxA  = (int*)alloc((size_t)N_DIR * 4);
    int* offsB = (int*)alloc((N_UND + 1) * 4);
    int* curB  = (int*)alloc(N_UND * 4);
    int* idxB  = (int*)alloc((size_t)N_ANG * 4);
    int* bsum  = (int*)alloc(256 * 4);
    int* bbase = (int*)alloc(256 * 4);
    int* srcA  = (int*)alloc((size_t)N_DIR * 4 * 4);
    int* srcB  = (int*)alloc((size_t)N_ANG * 4 * 4);
    unsigned short* acw1cT = (unsigned short*)alloc((size_t)4 * 64 * 192 * 2);
    unsigned short* acw1gT = (unsigned short*)alloc((size_t)4 * 64 * 192 * 2);
    unsigned short* acw2cT = (unsigned short*)alloc((size_t)4 * 64 * 64 * 2);
    unsigned short* acw2gT = (unsigned short*)alloc((size_t)4 * 64 * 64 * 2);
    unsigned short* acoT   = (unsigned short*)alloc((size_t)4 * 64 * 64 * 2);
    unsigned short* bcw1cT = (unsigned short*)alloc((size_t)3 * 64 * 256 * 2);
    unsigned short* bcw1gT = (unsigned short*)alloc((size_t)3 * 64 * 256 * 2);
    unsigned short* bcw2cT = (unsigned short*)alloc((size_t)3 * 64 * 64 * 2);
    unsigned short* bcw2gT = (unsigned short*)alloc((size_t)3 * 64 * 64 * 2);
    unsigned short* bcoT   = (unsigned short*)alloc((size_t)3 * 64 * 64 * 2);
    unsigned short* anwcT  = (unsigned short*)alloc((size_t)3 * 64 * 256 * 2);
    unsigned short* anwgT  = (unsigned short*)alloc((size_t)3 * 64 * 256 * 2);

    // CSR build (idx needed by tables + permuted angle init)
    hipMemsetAsync(curA, 0, N_ATOMS * 4, stream);
    k_count<<<(N_DIR + 255) / 256, 256, 0, stream>>>(agraph, 2, N_DIR, curA);
    k_bsum <<<N_ATOMS / 256, 256, 0, stream>>>(curA, bsum);
    k_bscan<<<1, 256, 0, stream>>>(bsum, bbase, N_ATOMS / 256, offsA + N_ATOMS);
    k_offs <<<N_ATOMS / 256, 256, 0, stream>>>(curA, bbase, offsA);
    hipMemsetAsync(curA, 0, N_ATOMS * 4, stream);
    k_fill<<<(N_DIR + 255) / 256, 256, 0, stream>>>(agraph, 2, N_DIR, offsA, curA, idxA);

    hipMemsetAsync(curB, 0, N_UND * 4, stream);
    k_count<<<(N_ANG + 255) / 256, 256, 0, stream>>>(bgb, 2, N_ANG, curB);
    k_bsum <<<N_UND / 256, 256, 0, stream>>>(curB, bsum);
    k_bscan<<<1, 256, 0, stream>>>(bsum, bbase, N_UND / 256, offsB + N_UND);
    k_offs <<<N_UND / 256, 256, 0, stream>>>(curB, bbase, offsB);
    hipMemsetAsync(curB, 0, N_UND * 4, stream);
    k_fill<<<(N_ANG + 255) / 256, 256, 0, stream>>>(bgb, 2, N_ANG, offsB, curB, idxB);

    k_mktabA<<<(N_DIR + 255) / 256, 256, 0, stream>>>(agraph, d2u, idxA, (int4*)srcA, N_DIR);
    k_mktabB<<<(N_ANG + 255) / 256, 256, 0, stream>>>(bga, bgb, idxB, (int4*)srcB, N_ANG);

    k_transconv2<<<(4 * 192 * 64 + 255) / 256, 256, 0, stream>>>(ac_cw1, ac_gw1, acw1cT, acw1gT, 192, 4 * 192 * 64);
    k_transconv2<<<(4 * 64 * 64 + 255) / 256, 256, 0, stream>>>(ac_cw2, ac_gw2, acw2cT, acw2gT, 64, 4 * 64 * 64);
    k_transconv <<<(4 * 64 * 64 + 255) / 256, 256, 0, stream>>>(ac_out, acoT, 64, 4 * 64 * 64);
    k_transconv2<<<(3 * 256 * 64 + 255) / 256, 256, 0, stream>>>(bc_cw1, bc_gw1, bcw1cT, bcw1gT, 256, 3 * 256 * 64);
    k_transconv2<<<(3 * 64 * 64 + 255) / 256, 256, 0, stream>>>(bc_cw2, bc_gw2, bcw2cT, bcw2gT, 64, 3 * 64 * 64);
    k_transconv <<<(3 * 64 * 64 + 255) / 256, 256, 0, stream>>>(bc_out, bcoT, 64, 3 * 64 * 64);
    k_transconv2<<<(3 * 256 * 64 + 255) / 256, 256, 0, stream>>>(an_cw, an_gw, anwcT, anwgT, 256, 3 * 256 * 64);

    k_embed<<<N_ATOMS * 64 / 256, 256, 0, stream>>>(emb, atomic_numbers, atomBf);
    k_smallmm3<<<N_UND * 64 / 256, 256, 0, stream>>>(bb_ag, bb_bg, Wb, Wbwag, Wbwbg,
                                                     bondBf, bwagBf, bwbgBf);
    k_smallmm_perm<<<N_ANG * 64 / 256, 256, 0, stream>>>(ang_b, Wa, idxB, angleS);

    // iteration 0 atom conv
    k_atom_conv<<<N_DIR / 64, 256, 0, stream>>>(
        atomBf, bondBf, bwagBf, srcA,
        acw1cT, acw1gT, acw2cT, acw2gT, acoT,
        ac_cb1, ac_cb2, ac_gb1, ac_gb2, updBuf);
    k_reduce<<<N_ATOMS * 8 / 256, 256, 0, stream>>>(updBuf, offsA, atomBf, N_ATOMS);

    const int NB_AN = N_ANG / 64;      // 4096
    const int NB_AC = N_DIR / 64;      // 2048
    for (int i = 0; i < 3; ++i){
        k_bond_conv<<<NB_AN, 256, 0, stream>>>(
            atomBf, bondBf, angleS, bwbgBf, srcB,
            bcw1cT + (size_t)i * 64 * 256, bcw1gT + (size_t)i * 64 * 256,
            bcw2cT + (size_t)i * 64 * 64,  bcw2gT + (size_t)i * 64 * 64,
            bcoT   + (size_t)i * 64 * 64,
            bc_cb1 + i * 64, bc_cb2 + i * 64, bc_gb1 + i * 64, bc_gb2 + i * 64, updBuf);
        k_reduce<<<N_UND * 8 / 256, 256, 0, stream>>>(updBuf, offsB, bondBf, N_UND);
        k_angle_atom<<<NB_AN + NB_AC, 256, 0, stream>>>(
            atomBf, bondBf, angleS, bwagBf, srcA, srcB,
            anwcT + (size_t)i * 64 * 256, anwgT + (size_t)i * 64 * 256,
            an_cb + i * 64, an_gb + i * 64,
            acw1cT + (size_t)(i + 1) * 64 * 192, acw1gT + (size_t)(i + 1) * 64 * 192,
            acw2cT + (size_t)(i + 1) * 64 * 64,  acw2gT + (size_t)(i + 1) * 64 * 64,
            acoT   + (size_t)(i + 1) * 64 * 64,
            ac_cb1 + (i + 1) * 64, ac_cb2 + (i + 1) * 64,
            ac_gb1 + (i + 1) * 64, ac_gb2 + (i + 1) * 64,
            updBuf, NB_AN);
        k_reduce<<<N_ATOMS * 8 / 256, 256, 0, stream>>>(updBuf, offsA, atomBf, N_ATOMS);
    }

    hipMemsetAsync(esum, 0, 128 * 4, stream);
    hipMemsetAsync(cnt,  0, 128 * 4, stream);
    k_readout<<<N_ATOMS * 64 / 256, 256, 0, stream>>>(
        atomBf, owners, ro_w1, ro_b1, ro_w2, ro_b2, ro_w3, ro_b3, esum, cnt);
    k_final<<<1, 128, 0, stream>>>(esum, cnt, (float*)d_out);
}

// Round 14
// 809.951 us; speedup vs baseline: 1.2255x; 1.0401x over previous
//
#include <hip/hip_runtime.h>
#include <hip/hip_bf16.h>

typedef float f32x4 __attribute__((ext_vector_type(4)));
typedef short s16x8 __attribute__((ext_vector_type(8)));
typedef unsigned int u32x4 __attribute__((ext_vector_type(4)));

#define DEV static __device__ __forceinline__

DEV unsigned short f2bf(float x){
    unsigned u = __builtin_bit_cast(unsigned, x);
    u += 0x7FFFu + ((u >> 16) & 1u);
    return (unsigned short)(u >> 16);
}
DEV float bf2f(unsigned short h){
    unsigned u = ((unsigned)h) << 16;
    return __builtin_bit_cast(float, u);
}
DEV float sigm_(float x){ return __builtin_amdgcn_rcpf(1.0f + __expf(-x)); }
DEV float silu_(float x){ return x * sigm_(x); }

DEV int xcd_swz(){
    int bid = blockIdx.x, nwg = gridDim.x;
    return (bid & 7) * (nwg >> 3) + (bid >> 3);
}

// ---------------- weight transpose kernels, grouped by shape
DEV void tc_one(const float* s, unsigned short* d, int K, int gid){
    int kn = K * 64;
    int b = gid / kn, rem = gid - b * kn;
    int k = rem >> 6, n = rem & 63;
    d[b * kn + n * K + k] = f2bf(s[gid]);
}
__global__ __launch_bounds__(256) void k_transconv2(const float* __restrict__ s1,
                                                    const float* __restrict__ s2,
                                                    unsigned short* __restrict__ d1,
                                                    unsigned short* __restrict__ d2,
                                                    int K, int total){
    int gid = blockIdx.x * 256 + threadIdx.x;
    if (gid >= total) return;
    tc_one(s1, d1, K, gid);
    tc_one(s2, d2, K, gid);
}
__global__ __launch_bounds__(256) void k_transconv4(const float* __restrict__ s1,
                                                    const float* __restrict__ s2,
                                                    const float* __restrict__ s3,
                                                    const float* __restrict__ s4,
                                                    unsigned short* __restrict__ d1,
                                                    unsigned short* __restrict__ d2,
                                                    unsigned short* __restrict__ d3,
                                                    unsigned short* __restrict__ d4,
                                                    int K, int total){
    int gid = blockIdx.x * 256 + threadIdx.x;
    if (gid >= total) return;
    tc_one(s1, d1, K, gid);
    tc_one(s2, d2, K, gid);
    tc_one(s3, d3, K, gid);
    tc_one(s4, d4, K, gid);
}
__global__ __launch_bounds__(256) void k_transconv3(const float* __restrict__ s1,
                                                    const float* __restrict__ s2,
                                                    const float* __restrict__ s3,
                                                    unsigned short* __restrict__ d1,
                                                    unsigned short* __restrict__ d2,
                                                    unsigned short* __restrict__ d3,
                                                    int K, int total){
    int gid = blockIdx.x * 256 + threadIdx.x;
    if (gid >= total) return;
    tc_one(s1, d1, K, gid);
    tc_one(s2, d2, K, gid);
    tc_one(s3, d3, K, gid);
}

__global__ __launch_bounds__(256) void k_embed(const float* __restrict__ emb,
                                               const int* __restrict__ z,
                                               unsigned short* __restrict__ out){
    int gid = blockIdx.x * 256 + threadIdx.x;
    int n = gid >> 6, f = gid & 63;
    out[gid] = f2bf(emb[z[n] * 64 + f]);
}

__global__ __launch_bounds__(256) void k_smallmm3(const float* __restrict__ bag,
                                                  const float* __restrict__ bbg,
                                                  const float* __restrict__ Wb,
                                                  const float* __restrict__ Wwag,
                                                  const float* __restrict__ Wwbg,
                                                  unsigned short* __restrict__ bond,
                                                  unsigned short* __restrict__ bwag,
                                                  unsigned short* __restrict__ bwbg){
    int gid = blockIdx.x * 256 + threadIdx.x;
    int r = gid >> 6, f = gid & 63;
    const float* a = bag + (size_t)r * 9;
    const float* b = bbg + (size_t)r * 9;
    float s1 = 0.f, s2 = 0.f, s3 = 0.f;
    #pragma unroll
    for (int k = 0; k < 9; ++k){
        float av = a[k];
        s1 += av * Wb[k * 64 + f];
        s2 += av * Wwag[k * 64 + f];
        s3 += b[k] * Wwbg[k * 64 + f];
    }
    bond[gid] = f2bf(s1);
    bwag[gid] = f2bf(s2);
    bwbg[gid] = f2bf(s3);
}

__global__ __launch_bounds__(256) void k_smallmm_perm(const float* __restrict__ bases,
                                                      const float* __restrict__ W,
                                                      const int* __restrict__ perm,
                                                      unsigned short* __restrict__ out){
    int gid = blockIdx.x * 256 + threadIdx.x;
    int r = gid >> 6, f = gid & 63;
    const float* b = bases + (size_t)perm[r] * 9;
    float acc = 0.f;
    #pragma unroll
    for (int k = 0; k < 9; ++k) acc += b[k] * W[k * 64 + f];
    out[gid] = f2bf(acc);
}

// ---------------- combined CSR build (A: edges by ag0, B: angles by bgi)
__global__ void k_count2(const int* __restrict__ agraph, const int* __restrict__ bgb,
                         int* __restrict__ cntA, int* __restrict__ cntB, int nA, int nB){
    int i = blockIdx.x * 256 + threadIdx.x;
    if (i < nA) atomicAdd(&cntA[agraph[2 * (size_t)i]], 1);
    else if (i < nA + nB){
        int j = i - nA;
        atomicAdd(&cntB[bgb[2 * (size_t)j]], 1);
    }
}

__global__ __launch_bounds__(256) void k_bsum2(const int* __restrict__ cntA,
                                               const int* __restrict__ cntB,
                                               int* __restrict__ bsumA,
                                               int* __restrict__ bsumB, int nbA){
    int b = blockIdx.x;
    const int* cnt; int* out; int idx;
    if (b < nbA){ cnt = cntA; out = bsumA; idx = b; }
    else        { cnt = cntB; out = bsumB; idx = b - nbA; }
    int i = idx * 256 + threadIdx.x;
    int v = cnt[i];
    #pragma unroll
    for (int off = 32; off > 0; off >>= 1) v += __shfl_down(v, off);
    __shared__ int ws[4];
    if ((threadIdx.x & 63) == 0) ws[threadIdx.x >> 6] = v;
    __syncthreads();
    if (threadIdx.x == 0) out[idx] = ws[0] + ws[1] + ws[2] + ws[3];
}

__global__ __launch_bounds__(256) void k_bscan2(const int* __restrict__ bsumA,
                                                const int* __restrict__ bsumB,
                                                int* __restrict__ bbaseA,
                                                int* __restrict__ bbaseB,
                                                int nbA, int nbB,
                                                int* __restrict__ totA,
                                                int* __restrict__ totB){
    __shared__ int sh[256];
    int t = threadIdx.x;
    // scan A
    int v = (t < nbA) ? bsumA[t] : 0;
    sh[t] = v;
    __syncthreads();
    for (int d = 1; d < 256; d <<= 1){
        int u = (t >= d) ? sh[t - d] : 0;
        __syncthreads();
        sh[t] += u;
        __syncthreads();
    }
    if (t < nbA) bbaseA[t] = sh[t] - v;
    if (t == nbA - 1) *totA = sh[t];
    __syncthreads();
    // scan B
    v = (t < nbB) ? bsumB[t] : 0;
    sh[t] = v;
    __syncthreads();
    for (int d = 1; d < 256; d <<= 1){
        int u = (t >= d) ? sh[t - d] : 0;
        __syncthreads();
        sh[t] += u;
        __syncthreads();
    }
    if (t < nbB) bbaseB[t] = sh[t] - v;
    if (t == nbB - 1) *totB = sh[t];
}

// also re-zeroes cur (cnt) for the fill pass
__global__ __launch_bounds__(256) void k_offs2(int* __restrict__ cntA, int* __restrict__ cntB,
                                               const int* __restrict__ bbaseA,
                                               const int* __restrict__ bbaseB,
                                               int* __restrict__ offsA,
                                               int* __restrict__ offsB, int nbA){
    __shared__ int sh[256];
    int b = blockIdx.x;
    int* cnt; const int* bbase; int* offs; int idx;
    if (b < nbA){ cnt = cntA; bbase = bbaseA; offs = offsA; idx = b; }
    else        { cnt = cntB; bbase = bbaseB; offs = offsB; idx = b - nbA; }
    int t = threadIdx.x;
    int i = idx * 256 + t;
    int v = cnt[i];
    sh[t] = v;
    __syncthreads();
    for (int d = 1; d < 256; d <<= 1){
        int u = (t >= d) ? sh[t - d] : 0;
        __syncthreads();
        sh[t] += u;
        __syncthreads();
    }
    offs[i] = bbase[idx] + sh[t] - v;
    cnt[i] = 0;
}

__global__ void k_fill2(const int* __restrict__ agraph, const int* __restrict__ bgb,
                        const int* __restrict__ offsA, const int* __restrict__ offsB,
                        int* __restrict__ curA, int* __restrict__ curB,
                        int* __restrict__ idxA, int* __restrict__ idxB, int nA, int nB){
    int i = blockIdx.x * 256 + threadIdx.x;
    if (i < nA){
        int d = agraph[2 * (size_t)i];
        int p = offsA[d] + atomicAdd(&curA[d], 1);
        idxA[p] = i;
    } else if (i < nA + nB){
        int j = i - nA;
        int d = bgb[2 * (size_t)j];
        int p = offsB[d] + atomicAdd(&curB[d], 1);
        idxB[p] = j;
    }
}

// combined source tables
__global__ void k_mktab2(const int* __restrict__ agraph, const int* __restrict__ d2u,
                         const int* __restrict__ idxA, int4* __restrict__ srcA,
                         const int* __restrict__ bga, const int* __restrict__ bgb,
                         const int* __restrict__ idxB, int4* __restrict__ srcB,
                         int nA, int nB){
    int i = blockIdx.x * 256 + threadIdx.x;
    if (i < nA){
        int e = idxA[i];
        int u = d2u[e];
        srcA[i] = make_int4(agraph[2 * e], u, agraph[2 * e + 1], u);
    } else if (i < nA + nB){
        int j = i - nA;
        int a = idxB[j];
        srcB[j] = make_int4(bgb[2 * a], bgb[2 * a + 1], j, bga[a]);
    }
}

// ---------------- gather-reduce (contiguous)
__global__ __launch_bounds__(256) void k_reduce(const unsigned short* __restrict__ upd,
                                                const int* __restrict__ offs,
                                                unsigned short* __restrict__ act, int nRows){
    int gid = blockIdx.x * 256 + threadIdx.x;
    int row = gid >> 3;
    if (row >= nRows) return;
    int c8 = (gid & 7) * 8;
    int o = offs[row], e = offs[row + 1];
    float acc[8] = {};
    for (int j = o; j < e; ++j){
        s16x8 v = *(const s16x8*)&upd[(size_t)j * 64 + c8];
        #pragma unroll
        for (int q = 0; q < 8; ++q) acc[q] += bf2f((unsigned short)v[q]);
    }
    s16x8 a = *(s16x8*)&act[(size_t)row * 64 + c8];
    #pragma unroll
    for (int q = 0; q < 8; ++q) a[q] = (short)f2bf(bf2f((unsigned short)a[q]) + acc[q]);
    *(s16x8*)&act[(size_t)row * 64 + c8] = a;
}

#define MFMA16(a,b,c) __builtin_amdgcn_mfma_f32_16x16x32_bf16(a,b,c,0,0,0)

// ================= atom-conv body (table-driven staging) =================
DEV void atom_body(unsigned short* smem, int bid,
    const unsigned short* atomBf, const unsigned short* bondBf,
    const unsigned short* bwagBf, const int* srcA,
    const unsigned short* w1cT, const unsigned short* w1gT,
    const unsigned short* w2cT, const unsigned short* w2gT,
    const unsigned short* woT,
    const float* cb1, const float* cb2, const float* gb1, const float* gb2,
    unsigned short* upd)
{
    unsigned short* ldsA  = smem;
    unsigned short* ldsHC = smem;
    unsigned short* ldsHG = smem + 4736;
    unsigned short* ldsV  = smem + 9472;
    unsigned short* ldsBw = smem + 14208;   // [64][68]
    const int tid = threadIdx.x;
    const int r0  = bid * 64;

    {
        const int lane8 = tid & 7;
        #pragma unroll
        for (int p = 0; p < 8; ++p){
            int cc = p * 32 + (tid >> 3);
            int q = cc >> 6, row = cc & 63;
            int s = srcA[(size_t)(r0 + row) * 4 + q];
            const unsigned short* buf = (q == 1 || q == 3) ? bondBf : atomBf;
            if (q == 3) buf = bwagBf;
            u32x4 v = *(const u32x4*)(buf + (size_t)s * 64 + lane8 * 8);
            if (q < 3) *(u32x4*)&ldsA[row * 200 + q * 64 + lane8 * 8] = v;
            else       *(u32x4*)&ldsBw[row * 68 + lane8 * 8] = v;
        }
    }
    __syncthreads();

    const int lane = tid & 63;
    const int r16  = lane & 15;
    const int grp  = lane >> 4;
    const int col  = (tid >> 6) * 16 + r16;

    f32x4 aC[4] = {}, aG[4] = {};
    #pragma unroll
    for (int kt = 0; kt < 6; ++kt){
        s16x8 bc = *(const s16x8*)&w1cT[col * 192 + kt * 32 + grp * 8];
        s16x8 bg = *(const s16x8*)&w1gT[col * 192 + kt * 32 + grp * 8];
        #pragma unroll
        for (int mt = 0; mt < 4; ++mt){
            s16x8 a = *(const s16x8*)&ldsA[(mt * 16 + r16) * 200 + kt * 32 + grp * 8];
            aC[mt] = MFMA16(a, bc, aC[mt]);
            aG[mt] = MFMA16(a, bg, aG[mt]);
        }
    }
    __syncthreads();   // ldsA dead; overlay writable

    const float bC1 = cb1[col], bG1 = gb1[col];
    #pragma unroll
    for (int mt = 0; mt < 4; ++mt){
        #pragma unroll
        for (int j = 0; j < 4; ++j){
            int row = mt * 16 + grp * 4 + j;
            ldsHC[row * 74 + col] = f2bf(silu_(aC[mt][j] + bC1));
            ldsHG[row * 74 + col] = f2bf(silu_(aG[mt][j] + bG1));
        }
    }
    __syncthreads();

    f32x4 oC[4] = {}, oG[4] = {};
    #pragma unroll
    for (int kt = 0; kt < 2; ++kt){
        s16x8 bc = *(const s16x8*)&w2cT[col * 64 + kt * 32 + grp * 8];
        s16x8 bg = *(const s16x8*)&w2gT[col * 64 + kt * 32 + grp * 8];
        #pragma unroll
        for (int mt = 0; mt < 4; ++mt){
            s16x8 hc = *(const s16x8*)&ldsHC[(mt * 16 + r16) * 74 + kt * 32 + grp * 8];
            s16x8 hg = *(const s16x8*)&ldsHG[(mt * 16 + r16) * 74 + kt * 32 + grp * 8];
            oC[mt] = MFMA16(hc, bc, oC[mt]);
            oG[mt] = MFMA16(hg, bg, oG[mt]);
        }
    }
    const float bC2 = cb2[col], bG2 = gb2[col];
    #pragma unroll
    for (int mt = 0; mt < 4; ++mt){
        #pragma unroll
        for (int j = 0; j < 4; ++j){
            int row = mt * 16 + grp * 4 + j;
            float v = silu_(oC[mt][j] + bC2) * sigm_(oG[mt][j] + bG2);
            v *= bf2f(ldsBw[row * 68 + col]);
            ldsV[row * 74 + col] = f2bf(v);
        }
    }
    __syncthreads();

    f32x4 oD[4] = {};
    #pragma unroll
    for (int kt = 0; kt < 2; ++kt){
        s16x8 bo = *(const s16x8*)&woT[col * 64 + kt * 32 + grp * 8];
        #pragma unroll
        for (int mt = 0; mt < 4; ++mt){
            s16x8 a = *(const s16x8*)&ldsV[(mt * 16 + r16) * 74 + kt * 32 + grp * 8];
            oD[mt] = MFMA16(a, bo, oD[mt]);
        }
    }
    #pragma unroll
    for (int mt = 0; mt < 4; ++mt){
        #pragma unroll
        for (int j = 0; j < 4; ++j){
            int row = mt * 16 + grp * 4 + j;
            upd[(size_t)(r0 + row) * 64 + col] = f2bf(oD[mt][j]);
        }
    }
}

// ================= angle body (table-driven, angle in sorted space) =================
DEV void angle_body(unsigned short* ldsA, int bid,
    const unsigned short* atomBf, const unsigned short* bondBf,
    unsigned short* angleS, const int* srcB,
    const unsigned short* wcT, const unsigned short* wgT,
    const float* cb, const float* gb)
{
    const int tid = threadIdx.x;
    const int r0  = bid * 64;

    {
        const int lane8 = tid & 7;
        #pragma unroll
        for (int p = 0; p < 8; ++p){
            int cc = p * 32 + (tid >> 3);
            int q = cc >> 6, row = cc & 63;
            int s = srcB[(size_t)(r0 + row) * 4 + q];
            const unsigned short* buf = (q < 2) ? bondBf : (q == 2 ? angleS : atomBf);
            u32x4 v = *(const u32x4*)(buf + (size_t)s * 64 + lane8 * 8);
            *(u32x4*)&ldsA[row * 264 + q * 64 + lane8 * 8] = v;
        }
    }
    __syncthreads();

    const int lane = tid & 63;
    const int r16  = lane & 15;
    const int grp  = lane >> 4;
    const int col  = (tid >> 6) * 16 + r16;

    f32x4 aC[4] = {}, aG[4] = {};
    #pragma unroll
    for (int kt = 0; kt < 8; ++kt){
        s16x8 bc = *(const s16x8*)&wcT[col * 256 + kt * 32 + grp * 8];
        s16x8 bg = *(const s16x8*)&wgT[col * 256 + kt * 32 + grp * 8];
        #pragma unroll
        for (int mt = 0; mt < 4; ++mt){
            s16x8 a = *(const s16x8*)&ldsA[(mt * 16 + r16) * 264 + kt * 32 + grp * 8];
            aC[mt] = MFMA16(a, bc, aC[mt]);
            aG[mt] = MFMA16(a, bg, aG[mt]);
        }
    }
    const float bC = cb[col], bG = gb[col];
    #pragma unroll
    for (int mt = 0; mt < 4; ++mt){
        #pragma unroll
        for (int j = 0; j < 4; ++j){
            int row = mt * 16 + grp * 4 + j;
            float oldv = bf2f(ldsA[row * 264 + 128 + col]);
            float v = silu_(aC[mt][j] + bC) * sigm_(aG[mt][j] + bG);
            angleS[(size_t)(r0 + row) * 64 + col] = f2bf(oldv + v);
        }
    }
}

// ---------------- standalone atom conv (first iteration)
__global__ __launch_bounds__(256, 4) void k_atom_conv(
    const unsigned short* __restrict__ atomBf, const unsigned short* __restrict__ bondBf,
    const unsigned short* __restrict__ bwagBf, const int* __restrict__ srcA,
    const unsigned short* __restrict__ w1cT, const unsigned short* __restrict__ w1gT,
    const unsigned short* __restrict__ w2cT, const unsigned short* __restrict__ w2gT,
    const unsigned short* __restrict__ woT,
    const float* __restrict__ cb1, const float* __restrict__ cb2,
    const float* __restrict__ gb1, const float* __restrict__ gb2,
    unsigned short* __restrict__ upd)
{
    __shared__ __align__(16) unsigned short smem[18560];
    atom_body(smem, xcd_swz(), atomBf, bondBf, bwagBf, srcA,
              w1cT, w1gT, w2cT, w2gT, woT, cb1, cb2, gb1, gb2, upd);
}

// ---------------- fused: angle update (iter i) + atom conv (iter i+1)
__global__ __launch_bounds__(256, 4) void k_angle_atom(
    const unsigned short* __restrict__ atomBf, const unsigned short* __restrict__ bondBf,
    unsigned short* __restrict__ angleS, const unsigned short* __restrict__ bwagBf,
    const int* __restrict__ srcA, const int* __restrict__ srcB,
    const unsigned short* __restrict__ an_wcT, const unsigned short* __restrict__ an_wgT,
    const float* __restrict__ an_cb, const float* __restrict__ an_gb,
    const unsigned short* __restrict__ ac_w1cT, const unsigned short* __restrict__ ac_w1gT,
    const unsigned short* __restrict__ ac_w2cT, const unsigned short* __restrict__ ac_w2gT,
    const unsigned short* __restrict__ ac_woT,
    const float* __restrict__ ac_cb1, const float* __restrict__ ac_cb2,
    const float* __restrict__ ac_gb1, const float* __restrict__ ac_gb2,
    unsigned short* __restrict__ upd, int nbAngle)
{
    __shared__ __align__(16) unsigned short smem[18560];
    int bid = blockIdx.x;
    if (bid < nbAngle){
        angle_body(smem, bid, atomBf, bondBf, angleS, srcB,
                   an_wcT, an_wgT, an_cb, an_gb);
    } else {
        atom_body(smem, bid - nbAngle, atomBf, bondBf, bwagBf, srcA,
                  ac_w1cT, ac_w1gT, ac_w2cT, ac_w2gT, ac_woT,
                  ac_cb1, ac_cb2, ac_gb1, ac_gb2, upd);
    }
}

// ---------------- bond conv (table-driven)
__global__ __launch_bounds__(256, 4) void k_bond_conv(
    const unsigned short* __restrict__ atomBf, const unsigned short* __restrict__ bondBf,
    const unsigned short* __restrict__ angleS, const unsigned short* __restrict__ bwbgBf,
    const int* __restrict__ srcB,
    const unsigned short* __restrict__ w1cT, const unsigned short* __restrict__ w1gT,
    const unsigned short* __restrict__ w2cT, const unsigned short* __restrict__ w2gT,
    const unsigned short* __restrict__ woT,
    const float* __restrict__ cb1, const float* __restrict__ cb2,
    const float* __restrict__ gb1, const float* __restrict__ gb2,
    unsigned short* __restrict__ upd)
{
    __shared__ __align__(16) unsigned short lds[16896];
    unsigned short* ldsA  = lds;
    unsigned short* ldsHC = lds;
    unsigned short* ldsHG = lds + 4736;
    unsigned short* ldsV  = lds + 9472;
    const int tid = threadIdx.x;
    const int r0  = xcd_swz() * 64;

    {
        const int lane8 = tid & 7;
        #pragma unroll
        for (int p = 0; p < 8; ++p){
            int cc = p * 32 + (tid >> 3);
            int q = cc >> 6, row = cc & 63;
            int s = srcB[(size_t)(r0 + row) * 4 + q];
            const unsigned short* buf = (q < 2) ? bondBf : (q == 2 ? angleS : atomBf);
            u32x4 v = *(const u32x4*)(buf + (size_t)s * 64 + lane8 * 8);
            *(u32x4*)&ldsA[row * 264 + q * 64 + lane8 * 8] = v;
        }
    }
    __syncthreads();

    const int lane = tid & 63;
    const int r16  = lane & 15;
    const int grp  = lane >> 4;
    const int col  = (tid >> 6) * 16 + r16;

    unsigned short bwv[16];
    #pragma unroll
    for (int mt = 0; mt < 4; ++mt)
        #pragma unroll
        for (int j = 0; j < 4; ++j){
            int row = mt * 16 + grp * 4 + j;
            bwv[mt * 4 + j] = bwbgBf[(size_t)srcB[(size_t)(r0 + row) * 4] * 64 + col];
        }

    f32x4 aC[4] = {}, aG[4] = {};
    #pragma unroll
    for (int kt = 0; kt < 8; ++kt){
        s16x8 bc = *(const s16x8*)&w1cT[col * 256 + kt * 32 + grp * 8];
        s16x8 bg = *(const s16x8*)&w1gT[col * 256 + kt * 32 + grp * 8];
        #pragma unroll
        for (int mt = 0; mt < 4; ++mt){
            s16x8 a = *(const s16x8*)&ldsA[(mt * 16 + r16) * 264 + kt * 32 + grp * 8];
            aC[mt] = MFMA16(a, bc, aC[mt]);
            aG[mt] = MFMA16(a, bg, aG[mt]);
        }
    }
    __syncthreads();

    const float bC1 = cb1[col], bG1 = gb1[col];
    #pragma unroll
    for (int mt = 0; mt < 4; ++mt){
        #pragma unroll
        for (int j = 0; j < 4; ++j){
            int row = mt * 16 + grp * 4 + j;
            ldsHC[row * 74 + col] = f2bf(silu_(aC[mt][j] + bC1));
            ldsHG[row * 74 + col] = f2bf(silu_(aG[mt][j] + bG1));
        }
    }
    __syncthreads();

    f32x4 oC[4] = {}, oG[4] = {};
    #pragma unroll
    for (int kt = 0; kt < 2; ++kt){
        s16x8 bc = *(const s16x8*)&w2cT[col * 64 + kt * 32 + grp * 8];
        s16x8 bg = *(const s16x8*)&w2gT[col * 64 + kt * 32 + grp * 8];
        #pragma unroll
        for (int mt = 0; mt < 4; ++mt){
            s16x8 hc = *(const s16x8*)&ldsHC[(mt * 16 + r16) * 74 + kt * 32 + grp * 8];
            s16x8 hg = *(const s16x8*)&ldsHG[(mt * 16 + r16) * 74 + kt * 32 + grp * 8];
            oC[mt] = MFMA16(hc, bc, oC[mt]);
            oG[mt] = MFMA16(hg, bg, oG[mt]);
        }
    }
    const float bC2 = cb2[col], bG2 = gb2[col];
    #pragma unroll
    for (int mt = 0; mt < 4; ++mt){
        #pragma unroll
        for (int j = 0; j < 4; ++j){
            int row = mt * 16 + grp * 4 + j;
            float v = silu_(oC[mt][j] + bC2) * sigm_(oG[mt][j] + bG2);
            v *= bf2f(bwv[mt * 4 + j]);
            ldsV[row * 74 + col] = f2bf(v);
        }
    }
    __syncthreads();

    f32x4 oD[4] = {};
    #pragma unroll
    for (int kt = 0; kt < 2; ++kt){
        s16x8 bo = *(const s16x8*)&woT[col * 64 + kt * 32 + grp * 8];
        #pragma unroll
        for (int mt = 0; mt < 4; ++mt){
            s16x8 a = *(const s16x8*)&ldsV[(mt * 16 + r16) * 74 + kt * 32 + grp * 8];
            oD[mt] = MFMA16(a, bo, oD[mt]);
        }
    }
    #pragma unroll
    for (int mt = 0; mt < 4; ++mt){
        #pragma unroll
        for (int j = 0; j < 4; ++j){
            int row = mt * 16 + grp * 4 + j;
            upd[(size_t)(r0 + row) * 64 + col] = f2bf(oD[mt][j]);
        }
    }
}

// ---------------- readout MLP + segmented sum
__global__ __launch_bounds__(256) void k_readout(
    const unsigned short* __restrict__ atomBf, const int* __restrict__ owners,
    const float* __restrict__ w1, const float* __restrict__ b1,
    const float* __restrict__ w2, const float* __restrict__ b2,
    const float* __restrict__ w3, const float* __restrict__ b3,
    float* __restrict__ esum, float* __restrict__ cnt)
{
    int gid  = blockIdx.x * 256 + threadIdx.x;
    int n    = gid >> 6;
    int lane = threadIdx.x & 63;
    float a = bf2f(atomBf[n * 64 + lane]);
    float acc = b1[lane];
    #pragma unroll
    for (int k = 0; k < 64; ++k) acc += __shfl(a, k) * w1[k * 64 + lane];
    float h = silu_(acc);
    acc = b2[lane];
    #pragma unroll
    for (int k = 0; k < 64; ++k) acc += __shfl(h, k) * w2[k * 64 + lane];
    h = silu_(acc);
    float p = h * w3[lane];
    #pragma unroll
    for (int off = 32; off > 0; off >>= 1) p += __shfl_xor(p, off);
    if (lane == 0){
        atomicAdd(&esum[owners[n]], p + b3[0]);
        atomicAdd(&cnt[owners[n]], 1.0f);
    }
}

__global__ void k_final(const float* __restrict__ esum, const float* __restrict__ cnt,
                        float* __restrict__ out){
    int i = threadIdx.x;
    if (i < 128) out[i] = esum[i] / fmaxf(cnt[i], 1.0f);
}

extern "C" void kernel_launch(void* const* d_in, const int* in_sizes, int n_in,
                              void* d_out, int out_size, void* d_ws, size_t ws_size,
                              hipStream_t stream)
{
    (void)in_sizes; (void)n_in; (void)out_size; (void)ws_size;
    const int N_ATOMS = 8192, N_UND = 65536, N_DIR = 131072, N_ANG = 262144;

    const int*   atomic_numbers = (const int*)  d_in[0];
    const float* bb_ag  = (const float*)d_in[1];
    const float* bb_bg  = (const float*)d_in[2];
    const float* ang_b  = (const float*)d_in[3];
    const int*   agraph = (const int*)  d_in[4];
    const int*   d2u    = (const int*)  d_in[5];
    const int*   bga    = (const int*)  d_in[6];
    const int*   bgb    = (const int*)  d_in[7];
    const int*   owners = (const int*)  d_in[8];
    const float* emb    = (const float*)d_in[9];
    const float* Wb     = (const float*)d_in[10];
    const float* Wa     = (const float*)d_in[11];
    const float* Wbwag  = (const float*)d_in[12];
    const float* Wbwbg  = (const float*)d_in[13];
    const float* ac_cw1 = (const float*)d_in[14];
    const float* ac_cb1 = (const float*)d_in[15];
    const float* ac_cw2 = (const float*)d_in[16];
    const float* ac_cb2 = (const float*)d_in[17];
    const float* ac_gw1 = (const float*)d_in[18];
    const float* ac_gb1 = (const float*)d_in[19];
    const float* ac_gw2 = (const float*)d_in[20];
    const float* ac_gb2 = (const float*)d_in[21];
    const float* ac_out = (const float*)d_in[22];
    const float* bc_cw1 = (const float*)d_in[23];
    const float* bc_cb1 = (const float*)d_in[24];
    const float* bc_cw2 = (const float*)d_in[25];
    const float* bc_cb2 = (const float*)d_in[26];
    const float* bc_gw1 = (const float*)d_in[27];
    const float* bc_gb1 = (const float*)d_in[28];
    const float* bc_gw2 = (const float*)d_in[29];
    const float* bc_gb2 = (const float*)d_in[30];
    const float* bc_out = (const float*)d_in[31];
    const float* an_cw  = (const float*)d_in[32];
    const float* an_cb  = (const float*)d_in[33];
    const float* an_gw  = (const float*)d_in[34];
    const float* an_gb  = (const float*)d_in[35];
    const float* ro_w1  = (const float*)d_in[36];
    const float* ro_b1  = (const float*)d_in[37];
    const float* ro_w2  = (const float*)d_in[38];
    const float* ro_b2  = (const float*)d_in[39];
    const float* ro_w3  = (const float*)d_in[40];
    const float* ro_b3  = (const float*)d_in[41];

    char* ws = (char*)d_ws;
    size_t off = 0;
    auto alloc = [&](size_t bytes) -> void* {
        void* p = ws + off;
        off = (off + bytes + 255) & ~(size_t)255;
        return p;
    };
    unsigned short* atomBf  = (unsigned short*)alloc((size_t)N_ATOMS * 64 * 2);
    unsigned short* bondBf  = (unsigned short*)alloc((size_t)N_UND   * 64 * 2);
    unsigned short* angleS  = (unsigned short*)alloc((size_t)N_ANG   * 64 * 2);
    unsigned short* bwagBf  = (unsigned short*)alloc((size_t)N_UND   * 64 * 2);
    unsigned short* bwbgBf  = (unsigned short*)alloc((size_t)N_UND   * 64 * 2);
    unsigned short* updBuf  = (unsigned short*)alloc((size_t)N_ANG   * 64 * 2);
    float* esum   = (float*)alloc(128 * 4);           // esum+cnt adjacent (one memset)
    float* cnt    = (float*)alloc(128 * 4);
    int* curA  = (int*)alloc(N_ATOMS * 4);            // curA+curB adjacent (one memset)
    int* curB  = (int*)alloc(N_UND * 4);
    int* offsA = (int*)alloc((N_ATOMS + 1) * 4);
    int* idxA  = (int*)alloc((size_t)N_DIR * 4);
    int* offsB = (int*)alloc((N_UND + 1) * 4);
    int* idxB  = (int*)alloc((size_t)N_ANG * 4);
    int* bsumA = (int*)alloc(256 * 4);
    int* bsumB = (int*)alloc(256 * 4);
    int* bbaseA= (int*)alloc(256 * 4);
    int* bbaseB= (int*)alloc(256 * 4);
    int* srcA  = (int*)alloc((size_t)N_DIR * 4 * 4);
    int* srcB  = (int*)alloc((size_t)N_ANG * 4 * 4);
    unsigned short* acw1cT = (unsigned short*)alloc((size_t)4 * 64 * 192 * 2);
    unsigned short* acw1gT = (unsigned short*)alloc((size_t)4 * 64 * 192 * 2);
    unsigned short* acw2cT = (unsigned short*)alloc((size_t)4 * 64 * 64 * 2);
    unsigned short* acw2gT = (unsigned short*)alloc((size_t)4 * 64 * 64 * 2);
    unsigned short* acoT   = (unsigned short*)alloc((size_t)4 * 64 * 64 * 2);
    unsigned short* bcw1cT = (unsigned short*)alloc((size_t)3 * 64 * 256 * 2);
    unsigned short* bcw1gT = (unsigned short*)alloc((size_t)3 * 64 * 256 * 2);
    unsigned short* bcw2cT = (unsigned short*)alloc((size_t)3 * 64 * 64 * 2);
    unsigned short* bcw2gT = (unsigned short*)alloc((size_t)3 * 64 * 64 * 2);
    unsigned short* bcoT   = (unsigned short*)alloc((size_t)3 * 64 * 64 * 2);
    unsigned short* anwcT  = (unsigned short*)alloc((size_t)3 * 64 * 256 * 2);
    unsigned short* anwgT  = (unsigned short*)alloc((size_t)3 * 64 * 256 * 2);

    // ---- combined CSR build ----
    hipMemsetAsync(curA, 0, (size_t)(N_ATOMS + N_UND) * 4, stream);
    k_count2<<<(N_DIR + N_ANG + 255) / 256, 256, 0, stream>>>(agraph, bgb, curA, curB, N_DIR, N_ANG);
    k_bsum2<<<N_ATOMS / 256 + N_UND / 256, 256, 0, stream>>>(curA, curB, bsumA, bsumB, N_ATOMS / 256);
    k_bscan2<<<1, 256, 0, stream>>>(bsumA, bsumB, bbaseA, bbaseB,
                                    N_ATOMS / 256, N_UND / 256,
                                    offsA + N_ATOMS, offsB + N_UND);
    k_offs2<<<N_ATOMS / 256 + N_UND / 256, 256, 0, stream>>>(curA, curB, bbaseA, bbaseB,
                                                             offsA, offsB, N_ATOMS / 256);
    k_fill2<<<(N_DIR + N_ANG + 255) / 256, 256, 0, stream>>>(agraph, bgb, offsA, offsB,
                                                             curA, curB, idxA, idxB, N_DIR, N_ANG);
    k_mktab2<<<(N_DIR + N_ANG + 255) / 256, 256, 0, stream>>>(agraph, d2u, idxA, (int4*)srcA,
                                                              bga, bgb, idxB, (int4*)srcB,
                                                              N_DIR, N_ANG);

    // ---- weight transposes, grouped ----
    k_transconv2<<<(4 * 192 * 64 + 255) / 256, 256, 0, stream>>>(ac_cw1, ac_gw1, acw1cT, acw1gT, 192, 4 * 192 * 64);
    k_transconv4<<<(3 * 256 * 64 + 255) / 256, 256, 0, stream>>>(bc_cw1, bc_gw1, an_cw, an_gw,
                                                                 bcw1cT, bcw1gT, anwcT, anwgT, 256, 3 * 256 * 64);
    k_transconv3<<<(4 * 64 * 64 + 255) / 256, 256, 0, stream>>>(ac_cw2, ac_gw2, ac_out,
                                                                acw2cT, acw2gT, acoT, 64, 4 * 64 * 64);
    k_transconv3<<<(3 * 64 * 64 + 255) / 256, 256, 0, stream>>>(bc_cw2, bc_gw2, bc_out,
                                                                bcw2cT, bcw2gT, bcoT, 64, 3 * 64 * 64);

    // ---- feature init ----
    k_embed<<<N_ATOMS * 64 / 256, 256, 0, stream>>>(emb, atomic_numbers, atomBf);
    k_smallmm3<<<N_UND * 64 / 256, 256, 0, stream>>>(bb_ag, bb_bg, Wb, Wbwag, Wbwbg,
                                                     bondBf, bwagBf, bwbgBf);
    k_smallmm_perm<<<N_ANG * 64 / 256, 256, 0, stream>>>(ang_b, Wa, idxB, angleS);

    // iteration 0 atom conv
    k_atom_conv<<<N_DIR / 64, 256, 0, stream>>>(
        atomBf, bondBf, bwagBf, srcA,
        acw1cT, acw1gT, acw2cT, acw2gT, acoT,
        ac_cb1, ac_cb2, ac_gb1, ac_gb2, updBuf);
    k_reduce<<<N_ATOMS * 8 / 256, 256, 0, stream>>>(updBuf, offsA, atomBf, N_ATOMS);

    const int NB_AN = N_ANG / 64;      // 4096
    const int NB_AC = N_DIR / 64;      // 2048
    for (int i = 0; i < 3; ++i){
        k_bond_conv<<<NB_AN, 256, 0, stream>>>(
            atomBf, bondBf, angleS, bwbgBf, srcB,
            bcw1cT + (size_t)i * 64 * 256, bcw1gT + (size_t)i * 64 * 256,
            bcw2cT + (size_t)i * 64 * 64,  bcw2gT + (size_t)i * 64 * 64,
            bcoT   + (size_t)i * 64 * 64,
            bc_cb1 + i * 64, bc_cb2 + i * 64, bc_gb1 + i * 64, bc_gb2 + i * 64, updBuf);
        k_reduce<<<N_UND * 8 / 256, 256, 0, stream>>>(updBuf, offsB, bondBf, N_UND);
        k_angle_atom<<<NB_AN + NB_AC, 256, 0, stream>>>(
            atomBf, bondBf, angleS, bwagBf, srcA, srcB,
            anwcT + (size_t)i * 64 * 256, anwgT + (size_t)i * 64 * 256,
            an_cb + i * 64, an_gb + i * 64,
            acw1cT + (size_t)(i + 1) * 64 * 192, acw1gT + (size_t)(i + 1) * 64 * 192,
            acw2cT + (size_t)(i + 1) * 64 * 64,  acw2gT + (size_t)(i + 1) * 64 * 64,
            acoT   + (size_t)(i + 1) * 64 * 64,
            ac_cb1 + (i + 1) * 64, ac_cb2 + (i + 1) * 64,
            ac_gb1 + (i + 1) * 64, ac_gb2 + (i + 1) * 64,
            updBuf, NB_AN);
        k_reduce<<<N_ATOMS * 8 / 256, 256, 0, stream>>>(updBuf, offsA, atomBf, N_ATOMS);
    }

    hipMemsetAsync(esum, 0, 256 * 4, stream);   // esum + cnt (adjacent)
    k_readout<<<N_ATOMS * 64 / 256, 256, 0, stream>>>(
        atomBf, owners, ro_w1, ro_b1, ro_w2, ro_b2, ro_w3, ro_b3, esum, cnt);
    k_final<<<1, 128, 0, stream>>>(esum, cnt, (float*)d_out);
}

// Round 15
// 784.968 us; speedup vs baseline: 1.2645x; 1.0318x over previous
//
#include <hip/hip_runtime.h>
#include <hip/hip_bf16.h>

typedef float f32x4 __attribute__((ext_vector_type(4)));
typedef short s16x8 __attribute__((ext_vector_type(8)));
typedef unsigned int u32x4 __attribute__((ext_vector_type(4)));

#define DEV static __device__ __forceinline__

DEV unsigned short f2bf(float x){
    unsigned u = __builtin_bit_cast(unsigned, x);
    u += 0x7FFFu + ((u >> 16) & 1u);
    return (unsigned short)(u >> 16);
}
DEV float bf2f(unsigned short h){
    unsigned u = ((unsigned)h) << 16;
    return __builtin_bit_cast(float, u);
}
DEV float sigm_(float x){ return __builtin_amdgcn_rcpf(1.0f + __expf(-x)); }
DEV float silu_(float x){ return x * sigm_(x); }

DEV int xcd_swz(){
    int bid = blockIdx.x, nwg = gridDim.x;
    return (bid & 7) * (nwg >> 3) + (bid >> 3);
}

// ---------------- all weight transposes in one kernel (block ranges)
DEV void tc_one(const float* s, unsigned short* d, int K, int gid){
    int kn = K * 64;
    int b = gid / kn, rem = gid - b * kn;
    int k = rem >> 6, n = rem & 63;
    d[b * kn + n * K + k] = f2bf(s[gid]);
}
__global__ __launch_bounds__(256) void k_transall(
    const float* __restrict__ ac_cw1, const float* __restrict__ ac_gw1,
    const float* __restrict__ bc_cw1, const float* __restrict__ bc_gw1,
    const float* __restrict__ an_cw,  const float* __restrict__ an_gw,
    const float* __restrict__ ac_cw2, const float* __restrict__ ac_gw2,
    const float* __restrict__ ac_out,
    const float* __restrict__ bc_cw2, const float* __restrict__ bc_gw2,
    const float* __restrict__ bc_out,
    unsigned short* __restrict__ acw1cT, unsigned short* __restrict__ acw1gT,
    unsigned short* __restrict__ bcw1cT, unsigned short* __restrict__ bcw1gT,
    unsigned short* __restrict__ anwcT,  unsigned short* __restrict__ anwgT,
    unsigned short* __restrict__ acw2cT, unsigned short* __restrict__ acw2gT,
    unsigned short* __restrict__ acoT,
    unsigned short* __restrict__ bcw2cT, unsigned short* __restrict__ bcw2gT,
    unsigned short* __restrict__ bcoT)
{
    const int NB1 = 192;   // 4*192*64 /256
    const int NB2 = 192;   // 3*256*64 /256
    const int NB3 = 64;    // 4*64*64 /256
    int b = blockIdx.x;
    if (b < NB1){
        int gid = b * 256 + threadIdx.x;
        tc_one(ac_cw1, acw1cT, 192, gid);
        tc_one(ac_gw1, acw1gT, 192, gid);
    } else if (b < NB1 + NB2){
        int gid = (b - NB1) * 256 + threadIdx.x;
        tc_one(bc_cw1, bcw1cT, 256, gid);
        tc_one(bc_gw1, bcw1gT, 256, gid);
        tc_one(an_cw,  anwcT,  256, gid);
        tc_one(an_gw,  anwgT,  256, gid);
    } else if (b < NB1 + NB2 + NB3){
        int gid = (b - NB1 - NB2) * 256 + threadIdx.x;
        tc_one(ac_cw2, acw2cT, 64, gid);
        tc_one(ac_gw2, acw2gT, 64, gid);
        tc_one(ac_out, acoT,   64, gid);
    } else {
        int gid = (b - NB1 - NB2 - NB3) * 256 + threadIdx.x;
        if (gid < 3 * 64 * 64){
            tc_one(bc_cw2, bcw2cT, 64, gid);
            tc_one(bc_gw2, bcw2gT, 64, gid);
            tc_one(bc_out, bcoT,   64, gid);
        }
    }
}

// ---------------- feature init: embed + bond features + permuted angle, one kernel
__global__ __launch_bounds__(256) void k_init(
    const float* __restrict__ emb, const int* __restrict__ z,
    const float* __restrict__ bag, const float* __restrict__ bbg,
    const float* __restrict__ Wb, const float* __restrict__ Wwag,
    const float* __restrict__ Wwbg,
    const float* __restrict__ angb, const float* __restrict__ Wa,
    const int* __restrict__ perm,
    unsigned short* __restrict__ atomBf, unsigned short* __restrict__ bond,
    unsigned short* __restrict__ bwag, unsigned short* __restrict__ bwbg,
    unsigned short* __restrict__ angleS, int nbEmb, int nbBond)
{
    int b = blockIdx.x;
    if (b < nbEmb){
        int gid = b * 256 + threadIdx.x;
        int n = gid >> 6, f = gid & 63;
        atomBf[gid] = f2bf(emb[z[n] * 64 + f]);
    } else if (b < nbEmb + nbBond){
        int gid = (b - nbEmb) * 256 + threadIdx.x;
        int r = gid >> 6, f = gid & 63;
        const float* a = bag + (size_t)r * 9;
        const float* bb = bbg + (size_t)r * 9;
        float s1 = 0.f, s2 = 0.f, s3 = 0.f;
        #pragma unroll
        for (int k = 0; k < 9; ++k){
            float av = a[k];
            s1 += av * Wb[k * 64 + f];
            s2 += av * Wwag[k * 64 + f];
            s3 += bb[k] * Wwbg[k * 64 + f];
        }
        bond[gid] = f2bf(s1);
        bwag[gid] = f2bf(s2);
        bwbg[gid] = f2bf(s3);
    } else {
        int gid = (b - nbEmb - nbBond) * 256 + threadIdx.x;
        int r = gid >> 6, f = gid & 63;
        const float* bb = angb + (size_t)perm[r] * 9;
        float acc = 0.f;
        #pragma unroll
        for (int k = 0; k < 9; ++k) acc += bb[k] * Wa[k * 64 + f];
        angleS[gid] = f2bf(acc);
    }
}

// ---------------- combined CSR build (A: edges by ag0, B: angles by bgi)
__global__ void k_count2(const int* __restrict__ agraph, const int* __restrict__ bgb,
                         int* __restrict__ cntA, int* __restrict__ cntB, int nA, int nB){
    int i = blockIdx.x * 256 + threadIdx.x;
    if (i < nA) atomicAdd(&cntA[agraph[2 * (size_t)i]], 1);
    else if (i < nA + nB){
        int j = i - nA;
        atomicAdd(&cntB[bgb[2 * (size_t)j]], 1);
    }
}

__global__ __launch_bounds__(256) void k_bsum2(const int* __restrict__ cntA,
                                               const int* __restrict__ cntB,
                                               int* __restrict__ bsumA,
                                               int* __restrict__ bsumB, int nbA){
    int b = blockIdx.x;
    const int* cnt; int* out; int idx;
    if (b < nbA){ cnt = cntA; out = bsumA; idx = b; }
    else        { cnt = cntB; out = bsumB; idx = b - nbA; }
    int i = idx * 256 + threadIdx.x;
    int v = cnt[i];
    #pragma unroll
    for (int off = 32; off > 0; off >>= 1) v += __shfl_down(v, off);
    __shared__ int ws[4];
    if ((threadIdx.x & 63) == 0) ws[threadIdx.x >> 6] = v;
    __syncthreads();
    if (threadIdx.x == 0) out[idx] = ws[0] + ws[1] + ws[2] + ws[3];
}

__global__ __launch_bounds__(256) void k_bscan2(const int* __restrict__ bsumA,
                                                const int* __restrict__ bsumB,
                                                int* __restrict__ bbaseA,
                                                int* __restrict__ bbaseB,
                                                int nbA, int nbB,
                                                int* __restrict__ totA,
                                                int* __restrict__ totB){
    __shared__ int sh[256];
    int t = threadIdx.x;
    int v = (t < nbA) ? bsumA[t] : 0;
    sh[t] = v;
    __syncthreads();
    for (int d = 1; d < 256; d <<= 1){
        int u = (t >= d) ? sh[t - d] : 0;
        __syncthreads();
        sh[t] += u;
        __syncthreads();
    }
    if (t < nbA) bbaseA[t] = sh[t] - v;
    if (t == nbA - 1) *totA = sh[t];
    __syncthreads();
    v = (t < nbB) ? bsumB[t] : 0;
    sh[t] = v;
    __syncthreads();
    for (int d = 1; d < 256; d <<= 1){
        int u = (t >= d) ? sh[t - d] : 0;
        __syncthreads();
        sh[t] += u;
        __syncthreads();
    }
    if (t < nbB) bbaseB[t] = sh[t] - v;
    if (t == nbB - 1) *totB = sh[t];
}

__global__ __launch_bounds__(256) void k_offs2(int* __restrict__ cntA, int* __restrict__ cntB,
                                               const int* __restrict__ bbaseA,
                                               const int* __restrict__ bbaseB,
                                               int* __restrict__ offsA,
                                               int* __restrict__ offsB, int nbA){
    __shared__ int sh[256];
    int b = blockIdx.x;
    int* cnt; const int* bbase; int* offs; int idx;
    if (b < nbA){ cnt = cntA; bbase = bbaseA; offs = offsA; idx = b; }
    else        { cnt = cntB; bbase = bbaseB; offs = offsB; idx = b - nbA; }
    int t = threadIdx.x;
    int i = idx * 256 + t;
    int v = cnt[i];
    sh[t] = v;
    __syncthreads();
    for (int d = 1; d < 256; d <<= 1){
        int u = (t >= d) ? sh[t - d] : 0;
        __syncthreads();
        sh[t] += u;
        __syncthreads();
    }
    offs[i] = bbase[idx] + sh[t] - v;
    cnt[i] = 0;
}

__global__ void k_fill2(const int* __restrict__ agraph, const int* __restrict__ bgb,
                        const int* __restrict__ offsA, const int* __restrict__ offsB,
                        int* __restrict__ curA, int* __restrict__ curB,
                        int* __restrict__ idxA, int* __restrict__ idxB, int nA, int nB){
    int i = blockIdx.x * 256 + threadIdx.x;
    if (i < nA){
        int d = agraph[2 * (size_t)i];
        int p = offsA[d] + atomicAdd(&curA[d], 1);
        idxA[p] = i;
    } else if (i < nA + nB){
        int j = i - nA;
        int d = bgb[2 * (size_t)j];
        int p = offsB[d] + atomicAdd(&curB[d], 1);
        idxB[p] = j;
    }
}

__global__ void k_mktab2(const int* __restrict__ agraph, const int* __restrict__ d2u,
                         const int* __restrict__ idxA, int4* __restrict__ srcA,
                         const int* __restrict__ bga, const int* __restrict__ bgb,
                         const int* __restrict__ idxB, int4* __restrict__ srcB,
                         int nA, int nB){
    int i = blockIdx.x * 256 + threadIdx.x;
    if (i < nA){
        int e = idxA[i];
        int u = d2u[e];
        srcA[i] = make_int4(agraph[2 * e], u, agraph[2 * e + 1], u);
    } else if (i < nA + nB){
        int j = i - nA;
        int a = idxB[j];
        srcB[j] = make_int4(bgb[2 * a], bgb[2 * a + 1], j, bga[a]);
    }
}

// ---------------- gather-reduce (contiguous)
__global__ __launch_bounds__(256) void k_reduce(const unsigned short* __restrict__ upd,
                                                const int* __restrict__ offs,
                                                unsigned short* __restrict__ act, int nRows){
    int gid = blockIdx.x * 256 + threadIdx.x;
    int row = gid >> 3;
    if (row >= nRows) return;
    int c8 = (gid & 7) * 8;
    int o = offs[row], e = offs[row + 1];
    float acc[8] = {};
    for (int j = o; j < e; ++j){
        s16x8 v = *(const s16x8*)&upd[(size_t)j * 64 + c8];
        #pragma unroll
        for (int q = 0; q < 8; ++q) acc[q] += bf2f((unsigned short)v[q]);
    }
    s16x8 a = *(s16x8*)&act[(size_t)row * 64 + c8];
    #pragma unroll
    for (int q = 0; q < 8; ++q) a[q] = (short)f2bf(bf2f((unsigned short)a[q]) + acc[q]);
    *(s16x8*)&act[(size_t)row * 64 + c8] = a;
}

#define MFMA16(a,b,c) __builtin_amdgcn_mfma_f32_16x16x32_bf16(a,b,c,0,0,0)

// ================= atom-conv body (table-driven staging) =================
DEV void atom_body(unsigned short* smem, int bid,
    const unsigned short* atomBf, const unsigned short* bondBf,
    const unsigned short* bwagBf, const int* srcA,
    const unsigned short* w1cT, const unsigned short* w1gT,
    const unsigned short* w2cT, const unsigned short* w2gT,
    const unsigned short* woT,
    const float* cb1, const float* cb2, const float* gb1, const float* gb2,
    unsigned short* upd)
{
    unsigned short* ldsA  = smem;
    unsigned short* ldsHC = smem;
    unsigned short* ldsHG = smem + 4736;
    unsigned short* ldsV  = smem + 9472;
    unsigned short* ldsBw = smem + 14208;   // [64][68]
    const int tid = threadIdx.x;
    const int r0  = bid * 64;

    {
        const int lane8 = tid & 7;
        #pragma unroll
        for (int p = 0; p < 8; ++p){
            int cc = p * 32 + (tid >> 3);
            int q = cc >> 6, row = cc & 63;
            int s = srcA[(size_t)(r0 + row) * 4 + q];
            const unsigned short* buf = (q == 1 || q == 3) ? bondBf : atomBf;
            if (q == 3) buf = bwagBf;
            u32x4 v = *(const u32x4*)(buf + (size_t)s * 64 + lane8 * 8);
            if (q < 3) *(u32x4*)&ldsA[row * 200 + q * 64 + lane8 * 8] = v;
            else       *(u32x4*)&ldsBw[row * 68 + lane8 * 8] = v;
        }
    }
    __syncthreads();

    const int lane = tid & 63;
    const int r16  = lane & 15;
    const int grp  = lane >> 4;
    const int col  = (tid >> 6) * 16 + r16;

    f32x4 aC[4] = {}, aG[4] = {};
    #pragma unroll
    for (int kt = 0; kt < 6; ++kt){
        s16x8 bc = *(const s16x8*)&w1cT[col * 192 + kt * 32 + grp * 8];
        s16x8 bg = *(const s16x8*)&w1gT[col * 192 + kt * 32 + grp * 8];
        #pragma unroll
        for (int mt = 0; mt < 4; ++mt){
            s16x8 a = *(const s16x8*)&ldsA[(mt * 16 + r16) * 200 + kt * 32 + grp * 8];
            aC[mt] = MFMA16(a, bc, aC[mt]);
            aG[mt] = MFMA16(a, bg, aG[mt]);
        }
    }
    __syncthreads();   // ldsA dead; overlay writable

    const float bC1 = cb1[col], bG1 = gb1[col];
    #pragma unroll
    for (int mt = 0; mt < 4; ++mt){
        #pragma unroll
        for (int j = 0; j < 4; ++j){
            int row = mt * 16 + grp * 4 + j;
            ldsHC[row * 74 + col] = f2bf(silu_(aC[mt][j] + bC1));
            ldsHG[row * 74 + col] = f2bf(silu_(aG[mt][j] + bG1));
        }
    }
    __syncthreads();

    f32x4 oC[4] = {}, oG[4] = {};
    #pragma unroll
    for (int kt = 0; kt < 2; ++kt){
        s16x8 bc = *(const s16x8*)&w2cT[col * 64 + kt * 32 + grp * 8];
        s16x8 bg = *(const s16x8*)&w2gT[col * 64 + kt * 32 + grp * 8];
        #pragma unroll
        for (int mt = 0; mt < 4; ++mt){
            s16x8 hc = *(const s16x8*)&ldsHC[(mt * 16 + r16) * 74 + kt * 32 + grp * 8];
            s16x8 hg = *(const s16x8*)&ldsHG[(mt * 16 + r16) * 74 + kt * 32 + grp * 8];
            oC[mt] = MFMA16(hc, bc, oC[mt]);
            oG[mt] = MFMA16(hg, bg, oG[mt]);
        }
    }
    const float bC2 = cb2[col], bG2 = gb2[col];
    #pragma unroll
    for (int mt = 0; mt < 4; ++mt){
        #pragma unroll
        for (int j = 0; j < 4; ++j){
            int row = mt * 16 + grp * 4 + j;
            float v = silu_(oC[mt][j] + bC2) * sigm_(oG[mt][j] + bG2);
            v *= bf2f(ldsBw[row * 68 + col]);
            ldsV[row * 74 + col] = f2bf(v);
        }
    }
    __syncthreads();

    f32x4 oD[4] = {};
    #pragma unroll
    for (int kt = 0; kt < 2; ++kt){
        s16x8 bo = *(const s16x8*)&woT[col * 64 + kt * 32 + grp * 8];
        #pragma unroll
        for (int mt = 0; mt < 4; ++mt){
            s16x8 a = *(const s16x8*)&ldsV[(mt * 16 + r16) * 74 + kt * 32 + grp * 8];
            oD[mt] = MFMA16(a, bo, oD[mt]);
        }
    }
    #pragma unroll
    for (int mt = 0; mt < 4; ++mt){
        #pragma unroll
        for (int j = 0; j < 4; ++j){
            int row = mt * 16 + grp * 4 + j;
            upd[(size_t)(r0 + row) * 64 + col] = f2bf(oD[mt][j]);
        }
    }
}

// ================= angle body (table-driven, angle in sorted space) =================
DEV void angle_body(unsigned short* ldsA, int bid,
    const unsigned short* atomBf, const unsigned short* bondBf,
    unsigned short* angleS, const int* srcB,
    const unsigned short* wcT, const unsigned short* wgT,
    const float* cb, const float* gb)
{
    const int tid = threadIdx.x;
    const int r0  = bid * 64;

    {
        const int lane8 = tid & 7;
        #pragma unroll
        for (int p = 0; p < 8; ++p){
            int cc = p * 32 + (tid >> 3);
            int q = cc >> 6, row = cc & 63;
            int s = srcB[(size_t)(r0 + row) * 4 + q];
            const unsigned short* buf = (q < 2) ? bondBf : (q == 2 ? angleS : atomBf);
            u32x4 v = *(const u32x4*)(buf + (size_t)s * 64 + lane8 * 8);
            *(u32x4*)&ldsA[row * 264 + q * 64 + lane8 * 8] = v;
        }
    }
    __syncthreads();

    const int lane = tid & 63;
    const int r16  = lane & 15;
    const int grp  = lane >> 4;
    const int col  = (tid >> 6) * 16 + r16;

    f32x4 aC[4] = {}, aG[4] = {};
    #pragma unroll
    for (int kt = 0; kt < 8; ++kt){
        s16x8 bc = *(const s16x8*)&wcT[col * 256 + kt * 32 + grp * 8];
        s16x8 bg = *(const s16x8*)&wgT[col * 256 + kt * 32 + grp * 8];
        #pragma unroll
        for (int mt = 0; mt < 4; ++mt){
            s16x8 a = *(const s16x8*)&ldsA[(mt * 16 + r16) * 264 + kt * 32 + grp * 8];
            aC[mt] = MFMA16(a, bc, aC[mt]);
            aG[mt] = MFMA16(a, bg, aG[mt]);
        }
    }
    const float bC = cb[col], bG = gb[col];
    #pragma unroll
    for (int mt = 0; mt < 4; ++mt){
        #pragma unroll
        for (int j = 0; j < 4; ++j){
            int row = mt * 16 + grp * 4 + j;
            float oldv = bf2f(ldsA[row * 264 + 128 + col]);
            float v = silu_(aC[mt][j] + bC) * sigm_(aG[mt][j] + bG);
            angleS[(size_t)(r0 + row) * 64 + col] = f2bf(oldv + v);
        }
    }
}

// ---------------- standalone atom conv (first iteration)
__global__ __launch_bounds__(256, 4) void k_atom_conv(
    const unsigned short* __restrict__ atomBf, const unsigned short* __restrict__ bondBf,
    const unsigned short* __restrict__ bwagBf, const int* __restrict__ srcA,
    const unsigned short* __restrict__ w1cT, const unsigned short* __restrict__ w1gT,
    const unsigned short* __restrict__ w2cT, const unsigned short* __restrict__ w2gT,
    const unsigned short* __restrict__ woT,
    const float* __restrict__ cb1, const float* __restrict__ cb2,
    const float* __restrict__ gb1, const float* __restrict__ gb2,
    unsigned short* __restrict__ upd)
{
    __shared__ __align__(16) unsigned short smem[18560];
    atom_body(smem, xcd_swz(), atomBf, bondBf, bwagBf, srcA,
              w1cT, w1gT, w2cT, w2gT, woT, cb1, cb2, gb1, gb2, upd);
}

// ---------------- fused: angle update (iter i) + atom conv (iter i+1)
__global__ __launch_bounds__(256, 4) void k_angle_atom(
    const unsigned short* __restrict__ atomBf, const unsigned short* __restrict__ bondBf,
    unsigned short* __restrict__ angleS, const unsigned short* __restrict__ bwagBf,
    const int* __restrict__ srcA, const int* __restrict__ srcB,
    const unsigned short* __restrict__ an_wcT, const unsigned short* __restrict__ an_wgT,
    const float* __restrict__ an_cb, const float* __restrict__ an_gb,
    const unsigned short* __restrict__ ac_w1cT, const unsigned short* __restrict__ ac_w1gT,
    const unsigned short* __restrict__ ac_w2cT, const unsigned short* __restrict__ ac_w2gT,
    const unsigned short* __restrict__ ac_woT,
    const float* __restrict__ ac_cb1, const float* __restrict__ ac_cb2,
    const float* __restrict__ ac_gb1, const float* __restrict__ ac_gb2,
    unsigned short* __restrict__ upd, int nbAngle)
{
    __shared__ __align__(16) unsigned short smem[18560];
    int bid = blockIdx.x;
    if (bid < nbAngle){
        angle_body(smem, bid, atomBf, bondBf, angleS, srcB,
                   an_wcT, an_wgT, an_cb, an_gb);
    } else {
        atom_body(smem, bid - nbAngle, atomBf, bondBf, bwagBf, srcA,
                  ac_w1cT, ac_w1gT, ac_w2cT, ac_w2gT, ac_woT,
                  ac_cb1, ac_cb2, ac_gb1, ac_gb2, upd);
    }
}

// ---------------- bond conv (table-driven)
__global__ __launch_bounds__(256, 4) void k_bond_conv(
    const unsigned short* __restrict__ atomBf, const unsigned short* __restrict__ bondBf,
    const unsigned short* __restrict__ angleS, const unsigned short* __restrict__ bwbgBf,
    const int* __restrict__ srcB,
    const unsigned short* __restrict__ w1cT, const unsigned short* __restrict__ w1gT,
    const unsigned short* __restrict__ w2cT, const unsigned short* __restrict__ w2gT,
    const unsigned short* __restrict__ woT,
    const float* __restrict__ cb1, const float* __restrict__ cb2,
    const float* __restrict__ gb1, const float* __restrict__ gb2,
    unsigned short* __restrict__ upd)
{
    __shared__ __align__(16) unsigned short lds[16896];
    unsigned short* ldsA  = lds;
    unsigned short* ldsHC = lds;
    unsigned short* ldsHG = lds + 4736;
    unsigned short* ldsV  = lds + 9472;
    const int tid = threadIdx.x;
    const int r0  = xcd_swz() * 64;

    {
        const int lane8 = tid & 7;
        #pragma unroll
        for (int p = 0; p < 8; ++p){
            int cc = p * 32 + (tid >> 3);
            int q = cc >> 6, row = cc & 63;
            int s = srcB[(size_t)(r0 + row) * 4 + q];
            const unsigned short* buf = (q < 2) ? bondBf : (q == 2 ? angleS : atomBf);
            u32x4 v = *(const u32x4*)(buf + (size_t)s * 64 + lane8 * 8);
            *(u32x4*)&ldsA[row * 264 + q * 64 + lane8 * 8] = v;
        }
    }
    __syncthreads();

    const int lane = tid & 63;
    const int r16  = lane & 15;
    const int grp  = lane >> 4;
    const int col  = (tid >> 6) * 16 + r16;

    unsigned short bwv[16];
    #pragma unroll
    for (int mt = 0; mt < 4; ++mt)
        #pragma unroll
        for (int j = 0; j < 4; ++j){
            int row = mt * 16 + grp * 4 + j;
            bwv[mt * 4 + j] = bwbgBf[(size_t)srcB[(size_t)(r0 + row) * 4] * 64 + col];
        }

    f32x4 aC[4] = {}, aG[4] = {};
    #pragma unroll
    for (int kt = 0; kt < 8; ++kt){
        s16x8 bc = *(const s16x8*)&w1cT[col * 256 + kt * 32 + grp * 8];
        s16x8 bg = *(const s16x8*)&w1gT[col * 256 + kt * 32 + grp * 8];
        #pragma unroll
        for (int mt = 0; mt < 4; ++mt){
            s16x8 a = *(const s16x8*)&ldsA[(mt * 16 + r16) * 264 + kt * 32 + grp * 8];
            aC[mt] = MFMA16(a, bc, aC[mt]);
            aG[mt] = MFMA16(a, bg, aG[mt]);
        }
    }
    __syncthreads();

    const float bC1 = cb1[col], bG1 = gb1[col];
    #pragma unroll
    for (int mt = 0; mt < 4; ++mt){
        #pragma unroll
        for (int j = 0; j < 4; ++j){
            int row = mt * 16 + grp * 4 + j;
            ldsHC[row * 74 + col] = f2bf(silu_(aC[mt][j] + bC1));
            ldsHG[row * 74 + col] = f2bf(silu_(aG[mt][j] + bG1));
        }
    }
    __syncthreads();

    f32x4 oC[4] = {}, oG[4] = {};
    #pragma unroll
    for (int kt = 0; kt < 2; ++kt){
        s16x8 bc = *(const s16x8*)&w2cT[col * 64 + kt * 32 + grp * 8];
        s16x8 bg = *(const s16x8*)&w2gT[col * 64 + kt * 32 + grp * 8];
        #pragma unroll
        for (int mt = 0; mt < 4; ++mt){
            s16x8 hc = *(const s16x8*)&ldsHC[(mt * 16 + r16) * 74 + kt * 32 + grp * 8];
            s16x8 hg = *(const s16x8*)&ldsHG[(mt * 16 + r16) * 74 + kt * 32 + grp * 8];
            oC[mt] = MFMA16(hc, bc, oC[mt]);
            oG[mt] = MFMA16(hg, bg, oG[mt]);
        }
    }
    const float bC2 = cb2[col], bG2 = gb2[col];
    #pragma unroll
    for (int mt = 0; mt < 4; ++mt){
        #pragma unroll
        for (int j = 0; j < 4; ++j){
            int row = mt * 16 + grp * 4 + j;
            float v = silu_(oC[mt][j] + bC2) * sigm_(oG[mt][j] + bG2);
            v *= bf2f(bwv[mt * 4 + j]);
            ldsV[row * 74 + col] = f2bf(v);
        }
    }
    __syncthreads();

    f32x4 oD[4] = {};
    #pragma unroll
    for (int kt = 0; kt < 2; ++kt){
        s16x8 bo = *(const s16x8*)&woT[col * 64 + kt * 32 + grp * 8];
        #pragma unroll
        for (int mt = 0; mt < 4; ++mt){
            s16x8 a = *(const s16x8*)&ldsV[(mt * 16 + r16) * 74 + kt * 32 + grp * 8];
            oD[mt] = MFMA16(a, bo, oD[mt]);
        }
    }
    #pragma unroll
    for (int mt = 0; mt < 4; ++mt){
        #pragma unroll
        for (int j = 0; j < 4; ++j){
            int row = mt * 16 + grp * 4 + j;
            upd[(size_t)(r0 + row) * 64 + col] = f2bf(oD[mt][j]);
        }
    }
}

// ---------------- readout MLP + fused final atom reduce + segmented sum
__global__ __launch_bounds__(256) void k_readout(
    const unsigned short* __restrict__ atomBf,
    const unsigned short* __restrict__ upd, const int* __restrict__ offsA,
    const int* __restrict__ owners,
    const float* __restrict__ w1, const float* __restrict__ b1,
    const float* __restrict__ w2, const float* __restrict__ b2,
    const float* __restrict__ w3, const float* __restrict__ b3,
    float* __restrict__ esum, float* __restrict__ cnt)
{
    int gid  = blockIdx.x * 256 + threadIdx.x;
    int n    = gid >> 6;
    int lane = threadIdx.x & 63;
    float a = bf2f(atomBf[n * 64 + lane]);
    int o = offsA[n], e = offsA[n + 1];
    for (int j = o; j < e; ++j)
        a += bf2f(upd[(size_t)j * 64 + lane]);     // coalesced 128B per step
    a = bf2f(f2bf(a));                              // match bf16 storage rounding
    float acc = b1[lane];
    #pragma unroll
    for (int k = 0; k < 64; ++k) acc += __shfl(a, k) * w1[k * 64 + lane];
    float h = silu_(acc);
    acc = b2[lane];
    #pragma unroll
    for (int k = 0; k < 64; ++k) acc += __shfl(h, k) * w2[k * 64 + lane];
    h = silu_(acc);
    float p = h * w3[lane];
    #pragma unroll
    for (int off = 32; off > 0; off >>= 1) p += __shfl_xor(p, off);
    if (lane == 0){
        atomicAdd(&esum[owners[n]], p + b3[0]);
        atomicAdd(&cnt[owners[n]], 1.0f);
    }
}

__global__ void k_final(const float* __restrict__ esum, const float* __restrict__ cnt,
                        float* __restrict__ out){
    int i = threadIdx.x;
    if (i < 128) out[i] = esum[i] / fmaxf(cnt[i], 1.0f);
}

extern "C" void kernel_launch(void* const* d_in, const int* in_sizes, int n_in,
                              void* d_out, int out_size, void* d_ws, size_t ws_size,
                              hipStream_t stream)
{
    (void)in_sizes; (void)n_in; (void)out_size; (void)ws_size;
    const int N_ATOMS = 8192, N_UND = 65536, N_DIR = 131072, N_ANG = 262144;

    const int*   atomic_numbers = (const int*)  d_in[0];
    const float* bb_ag  = (const float*)d_in[1];
    const float* bb_bg  = (const float*)d_in[2];
    const float* ang_b  = (const float*)d_in[3];
    const int*   agraph = (const int*)  d_in[4];
    const int*   d2u    = (const int*)  d_in[5];
    const int*   bga    = (const int*)  d_in[6];
    const int*   bgb    = (const int*)  d_in[7];
    const int*   owners = (const int*)  d_in[8];
    const float* emb    = (const float*)d_in[9];
    const float* Wb     = (const float*)d_in[10];
    const float* Wa     = (const float*)d_in[11];
    const float* Wbwag  = (const float*)d_in[12];
    const float* Wbwbg  = (const float*)d_in[13];
    const float* ac_cw1 = (const float*)d_in[14];
    const float* ac_cb1 = (const float*)d_in[15];
    const float* ac_cw2 = (const float*)d_in[16];
    const float* ac_cb2 = (const float*)d_in[17];
    const float* ac_gw1 = (const float*)d_in[18];
    const float* ac_gb1 = (const float*)d_in[19];
    const float* ac_gw2 = (const float*)d_in[20];
    const float* ac_gb2 = (const float*)d_in[21];
    const float* ac_out = (const float*)d_in[22];
    const float* bc_cw1 = (const float*)d_in[23];
    const float* bc_cb1 = (const float*)d_in[24];
    const float* bc_cw2 = (const float*)d_in[25];
    const float* bc_cb2 = (const float*)d_in[26];
    const float* bc_gw1 = (const float*)d_in[27];
    const float* bc_gb1 = (const float*)d_in[28];
    const float* bc_gw2 = (const float*)d_in[29];
    const float* bc_gb2 = (const float*)d_in[30];
    const float* bc_out = (const float*)d_in[31];
    const float* an_cw  = (const float*)d_in[32];
    const float* an_cb  = (const float*)d_in[33];
    const float* an_gw  = (const float*)d_in[34];
    const float* an_gb  = (const float*)d_in[35];
    const float* ro_w1  = (const float*)d_in[36];
    const float* ro_b1  = (const float*)d_in[37];
    const float* ro_w2  = (const float*)d_in[38];
    const float* ro_b2  = (const float*)d_in[39];
    const float* ro_w3  = (const float*)d_in[40];
    const float* ro_b3  = (const float*)d_in[41];

    char* ws = (char*)d_ws;
    size_t off = 0;
    auto alloc = [&](size_t bytes) -> void* {
        void* p = ws + off;
        off = (off + bytes + 255) & ~(size_t)255;
        return p;
    };
    unsigned short* atomBf  = (unsigned short*)alloc((size_t)N_ATOMS * 64 * 2);
    unsigned short* bondBf  = (unsigned short*)alloc((size_t)N_UND   * 64 * 2);
    unsigned short* angleS  = (unsigned short*)alloc((size_t)N_ANG   * 64 * 2);
    unsigned short* bwagBf  = (unsigned short*)alloc((size_t)N_UND   * 64 * 2);
    unsigned short* bwbgBf  = (unsigned short*)alloc((size_t)N_UND   * 64 * 2);
    unsigned short* updBuf  = (unsigned short*)alloc((size_t)N_ANG   * 64 * 2);
    float* esum   = (float*)alloc(128 * 4);
    float* cnt    = (float*)alloc(128 * 4);
    int* curA  = (int*)alloc(N_ATOMS * 4);
    int* curB  = (int*)alloc(N_UND * 4);
    int* offsA = (int*)alloc((N_ATOMS + 1) * 4);
    int* idxA  = (int*)alloc((size_t)N_DIR * 4);
    int* offsB = (int*)alloc((N_UND + 1) * 4);
    int* idxB  = (int*)alloc((size_t)N_ANG * 4);
    int* bsumA = (int*)alloc(256 * 4);
    int* bsumB = (int*)alloc(256 * 4);
    int* bbaseA= (int*)alloc(256 * 4);
    int* bbaseB= (int*)alloc(256 * 4);
    int* srcA  = (int*)alloc((size_t)N_DIR * 4 * 4);
    int* srcB  = (int*)alloc((size_t)N_ANG * 4 * 4);
    unsigned short* acw1cT = (unsigned short*)alloc((size_t)4 * 64 * 192 * 2);
    unsigned short* acw1gT = (unsigned short*)alloc((size_t)4 * 64 * 192 * 2);
    unsigned short* acw2cT = (unsigned short*)alloc((size_t)4 * 64 * 64 * 2);
    unsigned short* acw2gT = (unsigned short*)alloc((size_t)4 * 64 * 64 * 2);
    unsigned short* acoT   = (unsigned short*)alloc((size_t)4 * 64 * 64 * 2);
    unsigned short* bcw1cT = (unsigned short*)alloc((size_t)3 * 64 * 256 * 2);
    unsigned short* bcw1gT = (unsigned short*)alloc((size_t)3 * 64 * 256 * 2);
    unsigned short* bcw2cT = (unsigned short*)alloc((size_t)3 * 64 * 64 * 2);
    unsigned short* bcw2gT = (unsigned short*)alloc((size_t)3 * 64 * 64 * 2);
    unsigned short* bcoT   = (unsigned short*)alloc((size_t)3 * 64 * 64 * 2);
    unsigned short* anwcT  = (unsigned short*)alloc((size_t)3 * 64 * 256 * 2);
    unsigned short* anwgT  = (unsigned short*)alloc((size_t)3 * 64 * 256 * 2);

    // ---- weight transposes (independent of CSR) ----
    k_transall<<<496, 256, 0, stream>>>(
        ac_cw1, ac_gw1, bc_cw1, bc_gw1, an_cw, an_gw,
        ac_cw2, ac_gw2, ac_out, bc_cw2, bc_gw2, bc_out,
        acw1cT, acw1gT, bcw1cT, bcw1gT, anwcT, anwgT,
        acw2cT, acw2gT, acoT, bcw2cT, bcw2gT, bcoT);

    // ---- combined CSR build ----
    hipMemsetAsync(curA, 0, (size_t)(N_ATOMS + N_UND) * 4, stream);
    k_count2<<<(N_DIR + N_ANG + 255) / 256, 256, 0, stream>>>(agraph, bgb, curA, curB, N_DIR, N_ANG);
    k_bsum2<<<N_ATOMS / 256 + N_UND / 256, 256, 0, stream>>>(curA, curB, bsumA, bsumB, N_ATOMS / 256);
    k_bscan2<<<1, 256, 0, stream>>>(bsumA, bsumB, bbaseA, bbaseB,
                                    N_ATOMS / 256, N_UND / 256,
                                    offsA + N_ATOMS, offsB + N_UND);
    k_offs2<<<N_ATOMS / 256 + N_UND / 256, 256, 0, stream>>>(curA, curB, bbaseA, bbaseB,
                                                             offsA, offsB, N_ATOMS / 256);
    k_fill2<<<(N_DIR + N_ANG + 255) / 256, 256, 0, stream>>>(agraph, bgb, offsA, offsB,
                                                             curA, curB, idxA, idxB, N_DIR, N_ANG);
    k_mktab2<<<(N_DIR + N_ANG + 255) / 256, 256, 0, stream>>>(agraph, d2u, idxA, (int4*)srcA,
                                                              bga, bgb, idxB, (int4*)srcB,
                                                              N_DIR, N_ANG);

    // ---- feature init (embed + bond feats + permuted angle) ----
    const int NB_EMB  = N_ATOMS * 64 / 256;   // 2048
    const int NB_BOND = N_UND * 64 / 256;     // 16384
    const int NB_ANGI = N_ANG * 64 / 256;     // 65536
    k_init<<<NB_EMB + NB_BOND + NB_ANGI, 256, 0, stream>>>(
        emb, atomic_numbers, bb_ag, bb_bg, Wb, Wbwag, Wbwbg,
        ang_b, Wa, idxB, atomBf, bondBf, bwagBf, bwbgBf, angleS,
        NB_EMB, NB_BOND);

    // iteration 0 atom conv
    k_atom_conv<<<N_DIR / 64, 256, 0, stream>>>(
        atomBf, bondBf, bwagBf, srcA,
        acw1cT, acw1gT, acw2cT, acw2gT, acoT,
        ac_cb1, ac_cb2, ac_gb1, ac_gb2, updBuf);
    k_reduce<<<N_ATOMS * 8 / 256, 256, 0, stream>>>(updBuf, offsA, atomBf, N_ATOMS);

    const int NB_AN = N_ANG / 64;      // 4096
    const int NB_AC = N_DIR / 64;      // 2048
    for (int i = 0; i < 3; ++i){
        k_bond_conv<<<NB_AN, 256, 0, stream>>>(
            atomBf, bondBf, angleS, bwbgBf, srcB,
            bcw1cT + (size_t)i * 64 * 256, bcw1gT + (size_t)i * 64 * 256,
            bcw2cT + (size_t)i * 64 * 64,  bcw2gT + (size_t)i * 64 * 64,
            bcoT   + (size_t)i * 64 * 64,
            bc_cb1 + i * 64, bc_cb2 + i * 64, bc_gb1 + i * 64, bc_gb2 + i * 64, updBuf);
        k_reduce<<<N_UND * 8 / 256, 256, 0, stream>>>(updBuf, offsB, bondBf, N_UND);
        k_angle_atom<<<NB_AN + NB_AC, 256, 0, stream>>>(
            atomBf, bondBf, angleS, bwagBf, srcA, srcB,
            anwcT + (size_t)i * 64 * 256, anwgT + (size_t)i * 64 * 256,
            an_cb + i * 64, an_gb + i * 64,
            acw1cT + (size_t)(i + 1) * 64 * 192, acw1gT + (size_t)(i + 1) * 64 * 192,
            acw2cT + (size_t)(i + 1) * 64 * 64,  acw2gT + (size_t)(i + 1) * 64 * 64,
            acoT   + (size_t)(i + 1) * 64 * 64,
            ac_cb1 + (i + 1) * 64, ac_cb2 + (i + 1) * 64,
            ac_gb1 + (i + 1) * 64, ac_gb2 + (i + 1) * 64,
            updBuf, NB_AN);
        if (i < 2)
            k_reduce<<<N_ATOMS * 8 / 256, 256, 0, stream>>>(updBuf, offsA, atomBf, N_ATOMS);
    }

    // final atom reduce fused into readout
    hipMemsetAsync(esum, 0, 256 * 4, stream);   // esum + cnt (adjacent)
    k_readout<<<N_ATOMS * 64 / 256, 256, 0, stream>>>(
        atomBf, updBuf, offsA, owners,
        ro_w1, ro_b1, ro_w2, ro_b2, ro_w3, ro_b3, esum, cnt);
    k_final<<<1, 128, 0, stream>>>(esum, cnt, (float*)d_out);
}

// Round 16
// 782.049 us; speedup vs baseline: 1.2692x; 1.0037x over previous
//
#include <hip/hip_runtime.h>
#include <hip/hip_bf16.h>

typedef float f32x4 __attribute__((ext_vector_type(4)));
typedef short s16x8 __attribute__((ext_vector_type(8)));
typedef unsigned int u32x4 __attribute__((ext_vector_type(4)));

#define DEV static __device__ __forceinline__

DEV unsigned short f2bf(float x){
    unsigned u = __builtin_bit_cast(unsigned, x);
    u += 0x7FFFu + ((u >> 16) & 1u);
    return (unsigned short)(u >> 16);
}
DEV float bf2f(unsigned short h){
    unsigned u = ((unsigned)h) << 16;
    return __builtin_bit_cast(float, u);
}
DEV float sigm_(float x){ return __builtin_amdgcn_rcpf(1.0f + __expf(-x)); }
DEV float silu_(float x){ return x * sigm_(x); }

DEV int xcd_swz(){
    int bid = blockIdx.x, nwg = gridDim.x;
    return (bid & 7) * (nwg >> 3) + (bid >> 3);
}

DEV void tc_one(const float* s, unsigned short* d, int K, int gid){
    int kn = K * 64;
    int b = gid / kn, rem = gid - b * kn;
    int k = rem >> 6, n = rem & 63;
    d[b * kn + n * K + k] = f2bf(s[gid]);
}

// ================= prologue 1: transposes | CSR count | embed+bond feature init =================
__global__ __launch_bounds__(256) void k_pro1(
    // transposes
    const float* __restrict__ ac_cw1, const float* __restrict__ ac_gw1,
    const float* __restrict__ bc_cw1, const float* __restrict__ bc_gw1,
    const float* __restrict__ an_cw,  const float* __restrict__ an_gw,
    const float* __restrict__ ac_cw2, const float* __restrict__ ac_gw2,
    const float* __restrict__ ac_out,
    const float* __restrict__ bc_cw2, const float* __restrict__ bc_gw2,
    const float* __restrict__ bc_out,
    unsigned short* __restrict__ acw1cT, unsigned short* __restrict__ acw1gT,
    unsigned short* __restrict__ bcw1cT, unsigned short* __restrict__ bcw1gT,
    unsigned short* __restrict__ anwcT,  unsigned short* __restrict__ anwgT,
    unsigned short* __restrict__ acw2cT, unsigned short* __restrict__ acw2gT,
    unsigned short* __restrict__ acoT,
    unsigned short* __restrict__ bcw2cT, unsigned short* __restrict__ bcw2gT,
    unsigned short* __restrict__ bcoT,
    // CSR count
    const int* __restrict__ agraph, const int* __restrict__ bgb,
    int* __restrict__ cntA, int* __restrict__ cntB, int nA, int nB,
    // embed + bond feature init
    const float* __restrict__ emb, const int* __restrict__ z,
    const float* __restrict__ bag, const float* __restrict__ bbg,
    const float* __restrict__ Wb, const float* __restrict__ Wwag,
    const float* __restrict__ Wwbg,
    unsigned short* __restrict__ atomBf, unsigned short* __restrict__ bond,
    unsigned short* __restrict__ bwag, unsigned short* __restrict__ bwbg,
    int nbEmb)
{
    const int NB_T1 = 192, NB_T2 = 192, NB_T3 = 64, NB_T4 = 48;   // transposes: 496
    const int NB_T  = NB_T1 + NB_T2 + NB_T3 + NB_T4;
    const int NB_CNT = 1536;                                       // (nA+nB)/256
    int b = blockIdx.x;
    if (b < NB_T1){
        int gid = b * 256 + threadIdx.x;
        tc_one(ac_cw1, acw1cT, 192, gid);
        tc_one(ac_gw1, acw1gT, 192, gid);
    } else if (b < NB_T1 + NB_T2){
        int gid = (b - NB_T1) * 256 + threadIdx.x;
        tc_one(bc_cw1, bcw1cT, 256, gid);
        tc_one(bc_gw1, bcw1gT, 256, gid);
        tc_one(an_cw,  anwcT,  256, gid);
        tc_one(an_gw,  anwgT,  256, gid);
    } else if (b < NB_T1 + NB_T2 + NB_T3){
        int gid = (b - NB_T1 - NB_T2) * 256 + threadIdx.x;
        tc_one(ac_cw2, acw2cT, 64, gid);
        tc_one(ac_gw2, acw2gT, 64, gid);
        tc_one(ac_out, acoT,   64, gid);
    } else if (b < NB_T){
        int gid = (b - NB_T1 - NB_T2 - NB_T3) * 256 + threadIdx.x;
        tc_one(bc_cw2, bcw2cT, 64, gid);
        tc_one(bc_gw2, bcw2gT, 64, gid);
        tc_one(bc_out, bcoT,   64, gid);
    } else if (b < NB_T + NB_CNT){
        int i = (b - NB_T) * 256 + threadIdx.x;
        if (i < nA) atomicAdd(&cntA[agraph[2 * (size_t)i]], 1);
        else {
            int j = i - nA;
            atomicAdd(&cntB[bgb[2 * (size_t)j]], 1);
        }
    } else if (b < NB_T + NB_CNT + nbEmb){
        int gid = (b - NB_T - NB_CNT) * 256 + threadIdx.x;
        int n = gid >> 6, f = gid & 63;
        atomBf[gid] = f2bf(emb[z[n] * 64 + f]);
    } else {
        int gid = (b - NB_T - NB_CNT - nbEmb) * 256 + threadIdx.x;
        int r = gid >> 6, f = gid & 63;
        const float* a  = bag + (size_t)r * 9;
        const float* bb = bbg + (size_t)r * 9;
        float s1 = 0.f, s2 = 0.f, s3 = 0.f;
        #pragma unroll
        for (int k = 0; k < 9; ++k){
            float av = a[k];
            s1 += av * Wb[k * 64 + f];
            s2 += av * Wwag[k * 64 + f];
            s3 += bb[k] * Wwbg[k * 64 + f];
        }
        bond[gid] = f2bf(s1);
        bwag[gid] = f2bf(s2);
        bwbg[gid] = f2bf(s3);
    }
}

// ================= prologue 2: source tables | permuted angle init =================
__global__ __launch_bounds__(256) void k_pro2(
    const int* __restrict__ agraph, const int* __restrict__ d2u,
    const int* __restrict__ idxA, int4* __restrict__ srcA,
    const int* __restrict__ bga, const int* __restrict__ bgb,
    const int* __restrict__ idxB, int4* __restrict__ srcB,
    int nA, int nB,
    const float* __restrict__ angb, const float* __restrict__ Wa,
    unsigned short* __restrict__ angleS)
{
    const int NB_TAB = 1536;   // (nA+nB)/256
    int b = blockIdx.x;
    if (b < NB_TAB){
        int i = b * 256 + threadIdx.x;
        if (i < nA){
            int e = idxA[i];
            int u = d2u[e];
            srcA[i] = make_int4(agraph[2 * e], u, agraph[2 * e + 1], u);
        } else {
            int j = i - nA;
            int a = idxB[j];
            srcB[j] = make_int4(bgb[2 * a], bgb[2 * a + 1], j, bga[a]);
        }
    } else {
        int gid = (b - NB_TAB) * 256 + threadIdx.x;
        int r = gid >> 6, f = gid & 63;
        const float* bb = angb + (size_t)idxB[r] * 9;
        float acc = 0.f;
        #pragma unroll
        for (int k = 0; k < 9; ++k) acc += bb[k] * Wa[k * 64 + f];
        angleS[gid] = f2bf(acc);
    }
}

// ---------------- CSR scan/fill (dependent chain)
__global__ __launch_bounds__(256) void k_bsum2(const int* __restrict__ cntA,
                                               const int* __restrict__ cntB,
                                               int* __restrict__ bsumA,
                                               int* __restrict__ bsumB, int nbA){
    int b = blockIdx.x;
    const int* cnt; int* out; int idx;
    if (b < nbA){ cnt = cntA; out = bsumA; idx = b; }
    else        { cnt = cntB; out = bsumB; idx = b - nbA; }
    int i = idx * 256 + threadIdx.x;
    int v = cnt[i];
    #pragma unroll
    for (int off = 32; off > 0; off >>= 1) v += __shfl_down(v, off);
    __shared__ int ws[4];
    if ((threadIdx.x & 63) == 0) ws[threadIdx.x >> 6] = v;
    __syncthreads();
    if (threadIdx.x == 0) out[idx] = ws[0] + ws[1] + ws[2] + ws[3];
}

__global__ __launch_bounds__(256) void k_bscan2(const int* __restrict__ bsumA,
                                                const int* __restrict__ bsumB,
                                                int* __restrict__ bbaseA,
                                                int* __restrict__ bbaseB,
                                                int nbA, int nbB,
                                                int* __restrict__ totA,
                                                int* __restrict__ totB){
    __shared__ int sh[256];
    int t = threadIdx.x;
    int v = (t < nbA) ? bsumA[t] : 0;
    sh[t] = v;
    __syncthreads();
    for (int d = 1; d < 256; d <<= 1){
        int u = (t >= d) ? sh[t - d] : 0;
        __syncthreads();
        sh[t] += u;
        __syncthreads();
    }
    if (t < nbA) bbaseA[t] = sh[t] - v;
    if (t == nbA - 1) *totA = sh[t];
    __syncthreads();
    v = (t < nbB) ? bsumB[t] : 0;
    sh[t] = v;
    __syncthreads();
    for (int d = 1; d < 256; d <<= 1){
        int u = (t >= d) ? sh[t - d] : 0;
        __syncthreads();
        sh[t] += u;
        __syncthreads();
    }
    if (t < nbB) bbaseB[t] = sh[t] - v;
    if (t == nbB - 1) *totB = sh[t];
}

__global__ __launch_bounds__(256) void k_offs2(int* __restrict__ cntA, int* __restrict__ cntB,
                                               const int* __restrict__ bbaseA,
                                               const int* __restrict__ bbaseB,
                                               int* __restrict__ offsA,
                                               int* __restrict__ offsB, int nbA){
    __shared__ int sh[256];
    int b = blockIdx.x;
    int* cnt; const int* bbase; int* offs; int idx;
    if (b < nbA){ cnt = cntA; bbase = bbaseA; offs = offsA; idx = b; }
    else        { cnt = cntB; bbase = bbaseB; offs = offsB; idx = b - nbA; }
    int t = threadIdx.x;
    int i = idx * 256 + t;
    int v = cnt[i];
    sh[t] = v;
    __syncthreads();
    for (int d = 1; d < 256; d <<= 1){
        int u = (t >= d) ? sh[t - d] : 0;
        __syncthreads();
        sh[t] += u;
        __syncthreads();
    }
    offs[i] = bbase[idx] + sh[t] - v;
    cnt[i] = 0;
}

__global__ void k_fill2(const int* __restrict__ agraph, const int* __restrict__ bgb,
                        const int* __restrict__ offsA, const int* __restrict__ offsB,
                        int* __restrict__ curA, int* __restrict__ curB,
                        int* __restrict__ idxA, int* __restrict__ idxB, int nA, int nB){
    int i = blockIdx.x * 256 + threadIdx.x;
    if (i < nA){
        int d = agraph[2 * (size_t)i];
        int p = offsA[d] + atomicAdd(&curA[d], 1);
        idxA[p] = i;
    } else if (i < nA + nB){
        int j = i - nA;
        int d = bgb[2 * (size_t)j];
        int p = offsB[d] + atomicAdd(&curB[d], 1);
        idxB[p] = j;
    }
}

// ---------------- gather-reduce (contiguous)
__global__ __launch_bounds__(256) void k_reduce(const unsigned short* __restrict__ upd,
                                                const int* __restrict__ offs,
                                                unsigned short* __restrict__ act, int nRows){
    int gid = blockIdx.x * 256 + threadIdx.x;
    int row = gid >> 3;
    if (row >= nRows) return;
    int c8 = (gid & 7) * 8;
    int o = offs[row], e = offs[row + 1];
    float acc[8] = {};
    for (int j = o; j < e; ++j){
        s16x8 v = *(const s16x8*)&upd[(size_t)j * 64 + c8];
        #pragma unroll
        for (int q = 0; q < 8; ++q) acc[q] += bf2f((unsigned short)v[q]);
    }
    s16x8 a = *(s16x8*)&act[(size_t)row * 64 + c8];
    #pragma unroll
    for (int q = 0; q < 8; ++q) a[q] = (short)f2bf(bf2f((unsigned short)a[q]) + acc[q]);
    *(s16x8*)&act[(size_t)row * 64 + c8] = a;
}

#define MFMA16(a,b,c) __builtin_amdgcn_mfma_f32_16x16x32_bf16(a,b,c,0,0,0)

// ================= atom-conv body (table-driven staging) =================
DEV void atom_body(unsigned short* smem, int bid,
    const unsigned short* atomBf, const unsigned short* bondBf,
    const unsigned short* bwagBf, const int* srcA,
    const unsigned short* w1cT, const unsigned short* w1gT,
    const unsigned short* w2cT, const unsigned short* w2gT,
    const unsigned short* woT,
    const float* cb1, const float* cb2, const float* gb1, const float* gb2,
    unsigned short* upd)
{
    unsigned short* ldsA  = smem;
    unsigned short* ldsHC = smem;
    unsigned short* ldsHG = smem + 4736;
    unsigned short* ldsV  = smem + 9472;
    unsigned short* ldsBw = smem + 14208;   // [64][68]
    const int tid = threadIdx.x;
    const int r0  = bid * 64;

    {
        const int lane8 = tid & 7;
        #pragma unroll
        for (int p = 0; p < 8; ++p){
            int cc = p * 32 + (tid >> 3);
            int q = cc >> 6, row = cc & 63;
            int s = srcA[(size_t)(r0 + row) * 4 + q];
            const unsigned short* buf = (q == 1 || q == 3) ? bondBf : atomBf;
            if (q == 3) buf = bwagBf;
            u32x4 v = *(const u32x4*)(buf + (size_t)s * 64 + lane8 * 8);
            if (q < 3) *(u32x4*)&ldsA[row * 200 + q * 64 + lane8 * 8] = v;
            else       *(u32x4*)&ldsBw[row * 68 + lane8 * 8] = v;
        }
    }
    __syncthreads();

    const int lane = tid & 63;
    const int r16  = lane & 15;
    const int grp  = lane >> 4;
    const int col  = (tid >> 6) * 16 + r16;

    f32x4 aC[4] = {}, aG[4] = {};
    #pragma unroll
    for (int kt = 0; kt < 6; ++kt){
        s16x8 bc = *(const s16x8*)&w1cT[col * 192 + kt * 32 + grp * 8];
        s16x8 bg = *(const s16x8*)&w1gT[col * 192 + kt * 32 + grp * 8];
        #pragma unroll
        for (int mt = 0; mt < 4; ++mt){
            s16x8 a = *(const s16x8*)&ldsA[(mt * 16 + r16) * 200 + kt * 32 + grp * 8];
            aC[mt] = MFMA16(a, bc, aC[mt]);
            aG[mt] = MFMA16(a, bg, aG[mt]);
        }
    }
    __syncthreads();   // ldsA dead; overlay writable

    const float bC1 = cb1[col], bG1 = gb1[col];
    #pragma unroll
    for (int mt = 0; mt < 4; ++mt){
        #pragma unroll
        for (int j = 0; j < 4; ++j){
            int row = mt * 16 + grp * 4 + j;
            ldsHC[row * 74 + col] = f2bf(silu_(aC[mt][j] + bC1));
            ldsHG[row * 74 + col] = f2bf(silu_(aG[mt][j] + bG1));
        }
    }
    __syncthreads();

    f32x4 oC[4] = {}, oG[4] = {};
    #pragma unroll
    for (int kt = 0; kt < 2; ++kt){
        s16x8 bc = *(const s16x8*)&w2cT[col * 64 + kt * 32 + grp * 8];
        s16x8 bg = *(const s16x8*)&w2gT[col * 64 + kt * 32 + grp * 8];
        #pragma unroll
        for (int mt = 0; mt < 4; ++mt){
            s16x8 hc = *(const s16x8*)&ldsHC[(mt * 16 + r16) * 74 + kt * 32 + grp * 8];
            s16x8 hg = *(const s16x8*)&ldsHG[(mt * 16 + r16) * 74 + kt * 32 + grp * 8];
            oC[mt] = MFMA16(hc, bc, oC[mt]);
            oG[mt] = MFMA16(hg, bg, oG[mt]);
        }
    }
    const float bC2 = cb2[col], bG2 = gb2[col];
    #pragma unroll
    for (int mt = 0; mt < 4; ++mt){
        #pragma unroll
        for (int j = 0; j < 4; ++j){
            int row = mt * 16 + grp * 4 + j;
            float v = silu_(oC[mt][j] + bC2) * sigm_(oG[mt][j] + bG2);
            v *= bf2f(ldsBw[row * 68 + col]);
            ldsV[row * 74 + col] = f2bf(v);
        }
    }
    __syncthreads();

    f32x4 oD[4] = {};
    #pragma unroll
    for (int kt = 0; kt < 2; ++kt){
        s16x8 bo = *(const s16x8*)&woT[col * 64 + kt * 32 + grp * 8];
        #pragma unroll
        for (int mt = 0; mt < 4; ++mt){
            s16x8 a = *(const s16x8*)&ldsV[(mt * 16 + r16) * 74 + kt * 32 + grp * 8];
            oD[mt] = MFMA16(a, bo, oD[mt]);
        }
    }
    #pragma unroll
    for (int mt = 0; mt < 4; ++mt){
        #pragma unroll
        for (int j = 0; j < 4; ++j){
            int row = mt * 16 + grp * 4 + j;
            upd[(size_t)(r0 + row) * 64 + col] = f2bf(oD[mt][j]);
        }
    }
}

// ================= angle body (table-driven, angle in sorted space) =================
DEV void angle_body(unsigned short* ldsA, int bid,
    const unsigned short* atomBf, const unsigned short* bondBf,
    unsigned short* angleS, const int* srcB,
    const unsigned short* wcT, const unsigned short* wgT,
    const float* cb, const float* gb)
{
    const int tid = threadIdx.x;
    const int r0  = bid * 64;

    {
        const int lane8 = tid & 7;
        #pragma unroll
        for (int p = 0; p < 8; ++p){
            int cc = p * 32 + (tid >> 3);
            int q = cc >> 6, row = cc & 63;
            int s = srcB[(size_t)(r0 + row) * 4 + q];
            const unsigned short* buf = (q < 2) ? bondBf : (q == 2 ? angleS : atomBf);
            u32x4 v = *(const u32x4*)(buf + (size_t)s * 64 + lane8 * 8);
            *(u32x4*)&ldsA[row * 264 + q * 64 + lane8 * 8] = v;
        }
    }
    __syncthreads();

    const int lane = tid & 63;
    const int r16  = lane & 15;
    const int grp  = lane >> 4;
    const int col  = (tid >> 6) * 16 + r16;

    f32x4 aC[4] = {}, aG[4] = {};
    #pragma unroll
    for (int kt = 0; kt < 8; ++kt){
        s16x8 bc = *(const s16x8*)&wcT[col * 256 + kt * 32 + grp * 8];
        s16x8 bg = *(const s16x8*)&wgT[col * 256 + kt * 32 + grp * 8];
        #pragma unroll
        for (int mt = 0; mt < 4; ++mt){
            s16x8 a = *(const s16x8*)&ldsA[(mt * 16 + r16) * 264 + kt * 32 + grp * 8];
            aC[mt] = MFMA16(a, bc, aC[mt]);
            aG[mt] = MFMA16(a, bg, aG[mt]);
        }
    }
    const float bC = cb[col], bG = gb[col];
    #pragma unroll
    for (int mt = 0; mt < 4; ++mt){
        #pragma unroll
        for (int j = 0; j < 4; ++j){
            int row = mt * 16 + grp * 4 + j;
            float oldv = bf2f(ldsA[row * 264 + 128 + col]);
            float v = silu_(aC[mt][j] + bC) * sigm_(aG[mt][j] + bG);
            angleS[(size_t)(r0 + row) * 64 + col] = f2bf(oldv + v);
        }
    }
}

// ---------------- standalone atom conv (first iteration)
__global__ __launch_bounds__(256, 4) void k_atom_conv(
    const unsigned short* __restrict__ atomBf, const unsigned short* __restrict__ bondBf,
    const unsigned short* __restrict__ bwagBf, const int* __restrict__ srcA,
    const unsigned short* __restrict__ w1cT, const unsigned short* __restrict__ w1gT,
    const unsigned short* __restrict__ w2cT, const unsigned short* __restrict__ w2gT,
    const unsigned short* __restrict__ woT,
    const float* __restrict__ cb1, const float* __restrict__ cb2,
    const float* __restrict__ gb1, const float* __restrict__ gb2,
    unsigned short* __restrict__ upd)
{
    __shared__ __align__(16) unsigned short smem[18560];
    atom_body(smem, xcd_swz(), atomBf, bondBf, bwagBf, srcA,
              w1cT, w1gT, w2cT, w2gT, woT, cb1, cb2, gb1, gb2, upd);
}

// ---------------- fused: angle update (iter i) + atom conv (iter i+1)
__global__ __launch_bounds__(256, 4) void k_angle_atom(
    const unsigned short* __restrict__ atomBf, const unsigned short* __restrict__ bondBf,
    unsigned short* __restrict__ angleS, const unsigned short* __restrict__ bwagBf,
    const int* __restrict__ srcA, const int* __restrict__ srcB,
    const unsigned short* __restrict__ an_wcT, const unsigned short* __restrict__ an_wgT,
    const float* __restrict__ an_cb, const float* __restrict__ an_gb,
    const unsigned short* __restrict__ ac_w1cT, const unsigned short* __restrict__ ac_w1gT,
    const unsigned short* __restrict__ ac_w2cT, const unsigned short* __restrict__ ac_w2gT,
    const unsigned short* __restrict__ ac_woT,
    const float* __restrict__ ac_cb1, const float* __restrict__ ac_cb2,
    const float* __restrict__ ac_gb1, const float* __restrict__ ac_gb2,
    unsigned short* __restrict__ upd, int nbAngle)
{
    __shared__ __align__(16) unsigned short smem[18560];
    int bid = blockIdx.x;
    if (bid < nbAngle){
        angle_body(smem, bid, atomBf, bondBf, angleS, srcB,
                   an_wcT, an_wgT, an_cb, an_gb);
    } else {
        atom_body(smem, bid - nbAngle, atomBf, bondBf, bwagBf, srcA,
                  ac_w1cT, ac_w1gT, ac_w2cT, ac_w2gT, ac_woT,
                  ac_cb1, ac_cb2, ac_gb1, ac_gb2, upd);
    }
}

// ---------------- bond conv (table-driven)
__global__ __launch_bounds__(256, 4) void k_bond_conv(
    const unsigned short* __restrict__ atomBf, const unsigned short* __restrict__ bondBf,
    const unsigned short* __restrict__ angleS, const unsigned short* __restrict__ bwbgBf,
    const int* __restrict__ srcB,
    const unsigned short* __restrict__ w1cT, const unsigned short* __restrict__ w1gT,
    const unsigned short* __restrict__ w2cT, const unsigned short* __restrict__ w2gT,
    const unsigned short* __restrict__ woT,
    const float* __restrict__ cb1, const float* __restrict__ cb2,
    const float* __restrict__ gb1, const float* __restrict__ gb2,
    unsigned short* __restrict__ upd)
{
    __shared__ __align__(16) unsigned short lds[16896];
    unsigned short* ldsA  = lds;
    unsigned short* ldsHC = lds;
    unsigned short* ldsHG = lds + 4736;
    unsigned short* ldsV  = lds + 9472;
    const int tid = threadIdx.x;
    const int r0  = xcd_swz() * 64;

    {
        const int lane8 = tid & 7;
        #pragma unroll
        for (int p = 0; p < 8; ++p){
            int cc = p * 32 + (tid >> 3);
            int q = cc >> 6, row = cc & 63;
            int s = srcB[(size_t)(r0 + row) * 4 + q];
            const unsigned short* buf = (q < 2) ? bondBf : (q == 2 ? angleS : atomBf);
            u32x4 v = *(const u32x4*)(buf + (size_t)s * 64 + lane8 * 8);
            *(u32x4*)&ldsA[row * 264 + q * 64 + lane8 * 8] = v;
        }
    }
    __syncthreads();

    const int lane = tid & 63;
    const int r16  = lane & 15;
    const int grp  = lane >> 4;
    const int col  = (tid >> 6) * 16 + r16;

    unsigned short bwv[16];
    #pragma unroll
    for (int mt = 0; mt < 4; ++mt)
        #pragma unroll
        for (int j = 0; j < 4; ++j){
            int row = mt * 16 + grp * 4 + j;
            bwv[mt * 4 + j] = bwbgBf[(size_t)srcB[(size_t)(r0 + row) * 4] * 64 + col];
        }

    f32x4 aC[4] = {}, aG[4] = {};
    #pragma unroll
    for (int kt = 0; kt < 8; ++kt){
        s16x8 bc = *(const s16x8*)&w1cT[col * 256 + kt * 32 + grp * 8];
        s16x8 bg = *(const s16x8*)&w1gT[col * 256 + kt * 32 + grp * 8];
        #pragma unroll
        for (int mt = 0; mt < 4; ++mt){
            s16x8 a = *(const s16x8*)&ldsA[(mt * 16 + r16) * 264 + kt * 32 + grp * 8];
            aC[mt] = MFMA16(a, bc, aC[mt]);
            aG[mt] = MFMA16(a, bg, aG[mt]);
        }
    }
    __syncthreads();

    const float bC1 = cb1[col], bG1 = gb1[col];
    #pragma unroll
    for (int mt = 0; mt < 4; ++mt){
        #pragma unroll
        for (int j = 0; j < 4; ++j){
            int row = mt * 16 + grp * 4 + j;
            ldsHC[row * 74 + col] = f2bf(silu_(aC[mt][j] + bC1));
            ldsHG[row * 74 + col] = f2bf(silu_(aG[mt][j] + bG1));
        }
    }
    __syncthreads();

    f32x4 oC[4] = {}, oG[4] = {};
    #pragma unroll
    for (int kt = 0; kt < 2; ++kt){
        s16x8 bc = *(const s16x8*)&w2cT[col * 64 + kt * 32 + grp * 8];
        s16x8 bg = *(const s16x8*)&w2gT[col * 64 + kt * 32 + grp * 8];
        #pragma unroll
        for (int mt = 0; mt < 4; ++mt){
            s16x8 hc = *(const s16x8*)&ldsHC[(mt * 16 + r16) * 74 + kt * 32 + grp * 8];
            s16x8 hg = *(const s16x8*)&ldsHG[(mt * 16 + r16) * 74 + kt * 32 + grp * 8];
            oC[mt] = MFMA16(hc, bc, oC[mt]);
            oG[mt] = MFMA16(hg, bg, oG[mt]);
        }
    }
    const float bC2 = cb2[col], bG2 = gb2[col];
    #pragma unroll
    for (int mt = 0; mt < 4; ++mt){
        #pragma unroll
        for (int j = 0; j < 4; ++j){
            int row = mt * 16 + grp * 4 + j;
            float v = silu_(oC[mt][j] + bC2) * sigm_(oG[mt][j] + bG2);
            v *= bf2f(bwv[mt * 4 + j]);
            ldsV[row * 74 + col] = f2bf(v);
        }
    }
    __syncthreads();

    f32x4 oD[4] = {};
    #pragma unroll
    for (int kt = 0; kt < 2; ++kt){
        s16x8 bo = *(const s16x8*)&woT[col * 64 + kt * 32 + grp * 8];
        #pragma unroll
        for (int mt = 0; mt < 4; ++mt){
            s16x8 a = *(const s16x8*)&ldsV[(mt * 16 + r16) * 74 + kt * 32 + grp * 8];
            oD[mt] = MFMA16(a, bo, oD[mt]);
        }
    }
    #pragma unroll
    for (int mt = 0; mt < 4; ++mt){
        #pragma unroll
        for (int j = 0; j < 4; ++j){
            int row = mt * 16 + grp * 4 + j;
            upd[(size_t)(r0 + row) * 64 + col] = f2bf(oD[mt][j]);
        }
    }
}

// ---------------- readout MLP + fused final atom reduce + segmented sum
__global__ __launch_bounds__(256) void k_readout(
    const unsigned short* __restrict__ atomBf,
    const unsigned short* __restrict__ upd, const int* __restrict__ offsA,
    const int* __restrict__ owners,
    const float* __restrict__ w1, const float* __restrict__ b1,
    const float* __restrict__ w2, const float* __restrict__ b2,
    const float* __restrict__ w3, const float* __restrict__ b3,
    float* __restrict__ esum, float* __restrict__ cnt)
{
    int gid  = blockIdx.x * 256 + threadIdx.x;
    int n    = gid >> 6;
    int lane = threadIdx.x & 63;
    float a = bf2f(atomBf[n * 64 + lane]);
    int o = offsA[n], e = offsA[n + 1];
    for (int j = o; j < e; ++j)
        a += bf2f(upd[(size_t)j * 64 + lane]);
    a = bf2f(f2bf(a));
    float acc = b1[lane];
    #pragma unroll
    for (int k = 0; k < 64; ++k) acc += __shfl(a, k) * w1[k * 64 + lane];
    float h = silu_(acc);
    acc = b2[lane];
    #pragma unroll
    for (int k = 0; k < 64; ++k) acc += __shfl(h, k) * w2[k * 64 + lane];
    h = silu_(acc);
    float p = h * w3[lane];
    #pragma unroll
    for (int off = 32; off > 0; off >>= 1) p += __shfl_xor(p, off);
    if (lane == 0){
        atomicAdd(&esum[owners[n]], p + b3[0]);
        atomicAdd(&cnt[owners[n]], 1.0f);
    }
}

__global__ void k_final(const float* __restrict__ esum, const float* __restrict__ cnt,
                        float* __restrict__ out){
    int i = threadIdx.x;
    if (i < 128) out[i] = esum[i] / fmaxf(cnt[i], 1.0f);
}

extern "C" void kernel_launch(void* const* d_in, const int* in_sizes, int n_in,
                              void* d_out, int out_size, void* d_ws, size_t ws_size,
                              hipStream_t stream)
{
    (void)in_sizes; (void)n_in; (void)out_size; (void)ws_size;
    const int N_ATOMS = 8192, N_UND = 65536, N_DIR = 131072, N_ANG = 262144;

    const int*   atomic_numbers = (const int*)  d_in[0];
    const float* bb_ag  = (const float*)d_in[1];
    const float* bb_bg  = (const float*)d_in[2];
    const float* ang_b  = (const float*)d_in[3];
    const int*   agraph = (const int*)  d_in[4];
    const int*   d2u    = (const int*)  d_in[5];
    const int*   bga    = (const int*)  d_in[6];
    const int*   bgb    = (const int*)  d_in[7];
    const int*   owners = (const int*)  d_in[8];
    const float* emb    = (const float*)d_in[9];
    const float* Wb     = (const float*)d_in[10];
    const float* Wa     = (const float*)d_in[11];
    const float* Wbwag  = (const float*)d_in[12];
    const float* Wbwbg  = (const float*)d_in[13];
    const float* ac_cw1 = (const float*)d_in[14];
    const float* ac_cb1 = (const float*)d_in[15];
    const float* ac_cw2 = (const float*)d_in[16];
    const float* ac_cb2 = (const float*)d_in[17];
    const float* ac_gw1 = (const float*)d_in[18];
    const float* ac_gb1 = (const float*)d_in[19];
    const float* ac_gw2 = (const float*)d_in[20];
    const float* ac_gb2 = (const float*)d_in[21];
    const float* ac_out = (const float*)d_in[22];
    const float* bc_cw1 = (const float*)d_in[23];
    const float* bc_cb1 = (const float*)d_in[24];
    const float* bc_cw2 = (const float*)d_in[25];
    const float* bc_cb2 = (const float*)d_in[26];
    const float* bc_gw1 = (const float*)d_in[27];
    const float* bc_gb1 = (const float*)d_in[28];
    const float* bc_gw2 = (const float*)d_in[29];
    const float* bc_gb2 = (const float*)d_in[30];
    const float* bc_out = (const float*)d_in[31];
    const float* an_cw  = (const float*)d_in[32];
    const float* an_cb  = (const float*)d_in[33];
    const float* an_gw  = (const float*)d_in[34];
    const float* an_gb  = (const float*)d_in[35];
    const float* ro_w1  = (const float*)d_in[36];
    const float* ro_b1  = (const float*)d_in[37];
    const float* ro_w2  = (const float*)d_in[38];
    const float* ro_b2  = (const float*)d_in[39];
    const float* ro_w3  = (const float*)d_in[40];
    const float* ro_b3  = (const float*)d_in[41];

    char* ws = (char*)d_ws;
    size_t off = 0;
    auto alloc = [&](size_t bytes) -> void* {
        void* p = ws + off;
        off = (off + bytes + 255) & ~(size_t)255;
        return p;
    };
    unsigned short* atomBf  = (unsigned short*)alloc((size_t)N_ATOMS * 64 * 2);
    unsigned short* bondBf  = (unsigned short*)alloc((size_t)N_UND   * 64 * 2);
    unsigned short* angleS  = (unsigned short*)alloc((size_t)N_ANG   * 64 * 2);
    unsigned short* bwagBf  = (unsigned short*)alloc((size_t)N_UND   * 64 * 2);
    unsigned short* bwbgBf  = (unsigned short*)alloc((size_t)N_UND   * 64 * 2);
    unsigned short* updBuf  = (unsigned short*)alloc((size_t)N_ANG   * 64 * 2);
    float* esum   = (float*)alloc(128 * 4);
    float* cnt    = (float*)alloc(128 * 4);
    int* curA  = (int*)alloc(N_ATOMS * 4);
    int* curB  = (int*)alloc(N_UND * 4);
    int* offsA = (int*)alloc((N_ATOMS + 1) * 4);
    int* idxA  = (int*)alloc((size_t)N_DIR * 4);
    int* offsB = (int*)alloc((N_UND + 1) * 4);
    int* idxB  = (int*)alloc((size_t)N_ANG * 4);
    int* bsumA = (int*)alloc(256 * 4);
    int* bsumB = (int*)alloc(256 * 4);
    int* bbaseA= (int*)alloc(256 * 4);
    int* bbaseB= (int*)alloc(256 * 4);
    int* srcA  = (int*)alloc((size_t)N_DIR * 4 * 4);
    int* srcB  = (int*)alloc((size_t)N_ANG * 4 * 4);
    unsigned short* acw1cT = (unsigned short*)alloc((size_t)4 * 64 * 192 * 2);
    unsigned short* acw1gT = (unsigned short*)alloc((size_t)4 * 64 * 192 * 2);
    unsigned short* acw2cT = (unsigned short*)alloc((size_t)4 * 64 * 64 * 2);
    unsigned short* acw2gT = (unsigned short*)alloc((size_t)4 * 64 * 64 * 2);
    unsigned short* acoT   = (unsigned short*)alloc((size_t)4 * 64 * 64 * 2);
    unsigned short* bcw1cT = (unsigned short*)alloc((size_t)3 * 64 * 256 * 2);
    unsigned short* bcw1gT = (unsigned short*)alloc((size_t)3 * 64 * 256 * 2);
    unsigned short* bcw2cT = (unsigned short*)alloc((size_t)3 * 64 * 64 * 2);
    unsigned short* bcw2gT = (unsigned short*)alloc((size_t)3 * 64 * 64 * 2);
    unsigned short* bcoT   = (unsigned short*)alloc((size_t)3 * 64 * 64 * 2);
    unsigned short* anwcT  = (unsigned short*)alloc((size_t)3 * 64 * 256 * 2);
    unsigned short* anwgT  = (unsigned short*)alloc((size_t)3 * 64 * 256 * 2);

    const int NB_EMB  = N_ATOMS * 64 / 256;   // 2048
    const int NB_BOND = N_UND * 64 / 256;     // 16384
    const int NB_ANGI = N_ANG * 64 / 256;     // 65536

    // ---- prologue 1: transposes | CSR count | embed + bond feats ----
    hipMemsetAsync(curA, 0, (size_t)(N_ATOMS + N_UND) * 4, stream);
    k_pro1<<<496 + 1536 + NB_EMB + NB_BOND, 256, 0, stream>>>(
        ac_cw1, ac_gw1, bc_cw1, bc_gw1, an_cw, an_gw,
        ac_cw2, ac_gw2, ac_out, bc_cw2, bc_gw2, bc_out,
        acw1cT, acw1gT, bcw1cT, bcw1gT, anwcT, anwgT,
        acw2cT, acw2gT, acoT, bcw2cT, bcw2gT, bcoT,
        agraph, bgb, curA, curB, N_DIR, N_ANG,
        emb, atomic_numbers, bb_ag, bb_bg, Wb, Wbwag, Wbwbg,
        atomBf, bondBf, bwagBf, bwbgBf, NB_EMB);

    // ---- CSR scan/fill chain ----
    k_bsum2<<<N_ATOMS / 256 + N_UND / 256, 256, 0, stream>>>(curA, curB, bsumA, bsumB, N_ATOMS / 256);
    k_bscan2<<<1, 256, 0, stream>>>(bsumA, bsumB, bbaseA, bbaseB,
                                    N_ATOMS / 256, N_UND / 256,
                                    offsA + N_ATOMS, offsB + N_UND);
    k_offs2<<<N_ATOMS / 256 + N_UND / 256, 256, 0, stream>>>(curA, curB, bbaseA, bbaseB,
                                                             offsA, offsB, N_ATOMS / 256);
    k_fill2<<<(N_DIR + N_ANG + 255) / 256, 256, 0, stream>>>(agraph, bgb, offsA, offsB,
                                                             curA, curB, idxA, idxB, N_DIR, N_ANG);

    // ---- prologue 2: source tables | permuted angle init ----
    k_pro2<<<1536 + NB_ANGI, 256, 0, stream>>>(
        agraph, d2u, idxA, (int4*)srcA, bga, bgb, idxB, (int4*)srcB,
        N_DIR, N_ANG, ang_b, Wa, angleS);

    // iteration 0 atom conv
    k_atom_conv<<<N_DIR / 64, 256, 0, stream>>>(
        atomBf, bondBf, bwagBf, srcA,
        acw1cT, acw1gT, acw2cT, acw2gT, acoT,
        ac_cb1, ac_cb2, ac_gb1, ac_gb2, updBuf);
    k_reduce<<<N_ATOMS * 8 / 256, 256, 0, stream>>>(updBuf, offsA, atomBf, N_ATOMS);

    const int NB_AN = N_ANG / 64;      // 4096
    const int NB_AC = N_DIR / 64;      // 2048
    for (int i = 0; i < 3; ++i){
        k_bond_conv<<<NB_AN, 256, 0, stream>>>(
            atomBf, bondBf, angleS, bwbgBf, srcB,
            bcw1cT + (size_t)i * 64 * 256, bcw1gT + (size_t)i * 64 * 256,
            bcw2cT + (size_t)i * 64 * 64,  bcw2gT + (size_t)i * 64 * 64,
            bcoT   + (size_t)i * 64 * 64,
            bc_cb1 + i * 64, bc_cb2 + i * 64, bc_gb1 + i * 64, bc_gb2 + i * 64, updBuf);
        k_reduce<<<N_UND * 8 / 256, 256, 0, stream>>>(updBuf, offsB, bondBf, N_UND);
        k_angle_atom<<<NB_AN + NB_AC, 256, 0, stream>>>(
            atomBf, bondBf, angleS, bwagBf, srcA, srcB,
            anwcT + (size_t)i * 64 * 256, anwgT + (size_t)i * 64 * 256,
            an_cb + i * 64, an_gb + i * 64,
            acw1cT + (size_t)(i + 1) * 64 * 192, acw1gT + (size_t)(i + 1) * 64 * 192,
            acw2cT + (size_t)(i + 1) * 64 * 64,  acw2gT + (size_t)(i + 1) * 64 * 64,
            acoT   + (size_t)(i + 1) * 64 * 64,
            ac_cb1 + (i + 1) * 64, ac_cb2 + (i + 1) * 64,
            ac_gb1 + (i + 1) * 64, ac_gb2 + (i + 1) * 64,
            updBuf, NB_AN);
        if (i < 2)
            k_reduce<<<N_ATOMS * 8 / 256, 256, 0, stream>>>(updBuf, offsA, atomBf, N_ATOMS);
    }

    // final atom reduce fused into readout
    hipMemsetAsync(esum, 0, 256 * 4, stream);
    k_readout<<<N_ATOMS * 64 / 256, 256, 0, stream>>>(
        atomBf, updBuf, offsA, owners,
        ro_w1, ro_b1, ro_w2, ro_b2, ro_w3, ro_b3, esum, cnt);
    k_final<<<1, 128, 0, stream>>>(esum, cnt, (float*)d_out);
}